// Round 4
// baseline (555.854 us; speedup 1.0000x reference)
//
#include <hip/hip_runtime.h>

#define NUSERS 100000
#define NITEMS 50000
#define NTOT   150000   // NUSERS + NITEMS
#define NBIC   20000
#define DIM    64
#define SCAN_B 1024
#define NPART  8        // one partition per XCD (blockIdx % 8 heuristic)

// concatenated row space: [adj rows | hv rows | hu rows]
#define HV_BASE  NTOT
#define HU_BASE  (NTOT + NBIC)
#define NROWS_ALL (NTOT + NBIC + NUSERS)   // 270000  (divisible by 8)

// ---------------------------------------------------------------------------
// Fused CSR build over all three graphs (concatenated row space, one packed
// edge array). histogram -> 2-level exclusive scan -> partitioned scatter.
// ---------------------------------------------------------------------------
__global__ void hist_fused(const int* __restrict__ adj_row,
                           const int* __restrict__ hv_row,
                           const int* __restrict__ hu_row,
                           int* __restrict__ cnt,
                           int e_adj, int e_hv, int e_hu) {
    int t = blockIdx.x * blockDim.x + threadIdx.x;
    int r;
    if (t < e_adj)                    r = adj_row[t];
    else if (t < e_adj + e_hv)        r = HV_BASE + hv_row[t - e_adj];
    else if (t < e_adj + e_hv + e_hu) r = HU_BASE + hu_row[t - e_adj - e_hv];
    else return;
    atomicAdd(&cnt[r], 1);
}

// per-1024-block exclusive scan; block totals to bsum
__global__ void scan1_kernel(const int* __restrict__ cnt, int* __restrict__ ex,
                             int* __restrict__ bsum, int n) {
    __shared__ int s[SCAN_B];
    int tid = threadIdx.x;
    int g = blockIdx.x * SCAN_B + tid;
    int v = (g < n) ? cnt[g] : 0;
    s[tid] = v;
    __syncthreads();
    for (int off = 1; off < SCAN_B; off <<= 1) {
        int t = (tid >= off) ? s[tid - off] : 0;
        __syncthreads();
        s[tid] += t;
        __syncthreads();
    }
    if (g < n) ex[g] = s[tid] - v;                 // exclusive within block
    if (tid == SCAN_B - 1) bsum[blockIdx.x] = s[tid];
}

// single-block exclusive scan of block sums (nb <= 1024)
__global__ void scan2_kernel(int* __restrict__ bsum, int nb) {
    __shared__ int s[SCAN_B];
    int tid = threadIdx.x;
    int v = (tid < nb) ? bsum[tid] : 0;
    s[tid] = v;
    __syncthreads();
    for (int off = 1; off < SCAN_B; off <<= 1) {
        int t = (tid >= off) ? s[tid - off] : 0;
        __syncthreads();
        s[tid] += t;
        __syncthreads();
    }
    if (tid < nb) bsum[tid] = s[tid] - v;
}

// add block offsets; also initialize the scatter cursor
__global__ void scan3_kernel(int* __restrict__ ex, int* __restrict__ cursor,
                             const int* __restrict__ bsum, int n) {
    int g = blockIdx.x * blockDim.x + threadIdx.x;
    if (g < n) {
        int v = ex[g] + bsum[g >> 10];
        ex[g] = v;
        cursor[g] = v;
    }
}

// Partitioned scatter: blocks with blockIdx%NPART==p handle only rows in
// partition p (contiguous 1/NPART slice of the concatenated row space), so
// each XCD's writes cluster in one contiguous slice of edges[] and merge in
// that XCD's L2 before write-back.
__global__ void scatter_part(const int* __restrict__ adj_row, const int* __restrict__ adj_col,
                             const float* __restrict__ adj_val,
                             const int* __restrict__ hv_row, const int* __restrict__ hv_col,
                             const float* __restrict__ hv_val,
                             const int* __restrict__ hu_row, const int* __restrict__ hu_col,
                             const float* __restrict__ hu_val,
                             int* __restrict__ cursor, int2* __restrict__ edges,
                             int e_adj, int e_hv, int e_hu, int blocks_per_part) {
    const int part  = blockIdx.x % NPART;          // → XCD (round-robin heuristic)
    const int bslot = blockIdx.x / NPART;
    const int rlo = part * (NROWS_ALL / NPART);
    const int rhi = rlo + (NROWS_ALL / NPART);
    const int e_all = e_adj + e_hv + e_hu;
    const int stride = blocks_per_part * blockDim.x;
    for (int t = bslot * blockDim.x + threadIdx.x; t < e_all; t += stride) {
        int r, idx, which;
        if (t < e_adj)             { idx = t;               r = adj_row[idx];           which = 0; }
        else if (t < e_adj + e_hv) { idx = t - e_adj;       r = HV_BASE + hv_row[idx];  which = 1; }
        else                       { idx = t - e_adj - e_hv; r = HU_BASE + hu_row[idx]; which = 2; }
        if (r < rlo || r >= rhi) continue;
        int c; float v;
        if (which == 0)      { c = adj_col[idx]; v = adj_val[idx]; }
        else if (which == 1) { c = hv_col[idx];  v = hv_val[idx];  }
        else                 { c = hu_col[idx];  v = hu_val[idx];  }
        int p = atomicAdd(&cursor[r], 1);
        edges[p] = make_int2(c, __float_as_int(v));
    }
}

// ---------------------------------------------------------------------------
// Gather SpMMs: 16 threads per output row; each thread owns one float4 chunk.
// edges[] holds packed (col, val); start/cnt are absolute into edges[].
// ---------------------------------------------------------------------------
__device__ __forceinline__ float4 f4zero() {
    float4 z; z.x = z.y = z.z = z.w = 0.f; return z;
}

// layer 1: source is the virtual concat(user_emb, item_emb)
__global__ void gather_layer1(const int* __restrict__ start, const int* __restrict__ cnt,
                              const int2* __restrict__ edges,
                              const float* __restrict__ user, const float* __restrict__ item,
                              float* __restrict__ out) {
    int gid = blockIdx.x * (blockDim.x >> 4) + (threadIdx.x >> 4);
    if (gid >= NTOT) return;
    int c = (threadIdx.x & 15) << 2;
    int s = start[gid], n = cnt[gid];
    float4 acc = f4zero();
    for (int j = s; j < s + n; ++j) {
        int2 e = edges[j];
        int cc = e.x;
        float v = __int_as_float(e.y);
        const float* src = (cc < NUSERS) ? user + (size_t)cc * DIM
                                         : item + (size_t)(cc - NUSERS) * DIM;
        float4 xv = *(const float4*)(src + c);
        acc.x += v * xv.x; acc.y += v * xv.y; acc.z += v * xv.z; acc.w += v * xv.w;
    }
    *(float4*)(out + (size_t)gid * DIM + c) = acc;
}

// generic gather: out[row] = sum val * x[col]
__global__ void gather_plain(const int* __restrict__ start, const int* __restrict__ cnt,
                             const int2* __restrict__ edges,
                             const float* __restrict__ x, float* __restrict__ out, int nrows) {
    int gid = blockIdx.x * (blockDim.x >> 4) + (threadIdx.x >> 4);
    if (gid >= nrows) return;
    int c = (threadIdx.x & 15) << 2;
    int s = start[gid], n = cnt[gid];
    float4 acc = f4zero();
    for (int j = s; j < s + n; ++j) {
        int2 e = edges[j];
        int cc = e.x;
        float v = __int_as_float(e.y);
        float4 xv = *(const float4*)(x + (size_t)cc * DIM + c);
        acc.x += v * xv.x; acc.y += v * xv.y; acc.z += v * xv.z; acc.w += v * xv.w;
    }
    *(float4*)(out + (size_t)gid * DIM + c) = acc;
}

// gather + row-degree normalization fused (deg = sum val, 0 -> 1)
__global__ void gather_norm(const int* __restrict__ start, const int* __restrict__ cnt,
                            const int2* __restrict__ edges,
                            const float* __restrict__ x, float* __restrict__ out, int nrows) {
    int gid = blockIdx.x * (blockDim.x >> 4) + (threadIdx.x >> 4);
    if (gid >= nrows) return;
    int c = (threadIdx.x & 15) << 2;
    int s = start[gid], n = cnt[gid];
    float4 acc = f4zero();
    float deg = 0.f;
    for (int j = s; j < s + n; ++j) {
        int2 e = edges[j];
        int cc = e.x;
        float v = __int_as_float(e.y);
        deg += v;
        float4 xv = *(const float4*)(x + (size_t)cc * DIM + c);
        acc.x += v * xv.x; acc.y += v * xv.y; acc.z += v * xv.z; acc.w += v * xv.w;
    }
    if (deg == 0.f) deg = 1.f;
    float inv = 1.f / deg;
    acc.x *= inv; acc.y *= inv; acc.z *= inv; acc.w *= inv;
    *(float4*)(out + (size_t)gid * DIM + c) = acc;
}

// layer 3 + full epilogue: out = 0.25*(x0 + e1 + e2 + e3) [+ ulocal for users]
__global__ void gather_final(const int* __restrict__ start, const int* __restrict__ cnt,
                             const int2* __restrict__ edges,
                             const float* __restrict__ T0, const float* __restrict__ T1,
                             const float* __restrict__ user, const float* __restrict__ item,
                             const float* __restrict__ ulocal, float* __restrict__ out) {
    int gid = blockIdx.x * (blockDim.x >> 4) + (threadIdx.x >> 4);
    if (gid >= NTOT) return;
    int c = (threadIdx.x & 15) << 2;
    int s = start[gid], n = cnt[gid];
    float4 acc = f4zero();
    for (int j = s; j < s + n; ++j) {
        int2 e = edges[j];
        int cc = e.x;
        float v = __int_as_float(e.y);
        float4 xv = *(const float4*)(T1 + (size_t)cc * DIM + c);
        acc.x += v * xv.x; acc.y += v * xv.y; acc.z += v * xv.z; acc.w += v * xv.w;
    }
    size_t o = (size_t)gid * DIM + c;
    float4 x0 = (gid < NUSERS) ? *(const float4*)(user + o)
                               : *(const float4*)(item + o - (size_t)NUSERS * DIM);
    float4 t0 = *(const float4*)(T0 + o);
    float4 t1 = *(const float4*)(T1 + o);
    float4 r;
    r.x = 0.25f * (x0.x + t0.x + t1.x + acc.x);
    r.y = 0.25f * (x0.y + t0.y + t1.y + acc.y);
    r.z = 0.25f * (x0.z + t0.z + t1.z + acc.z);
    r.w = 0.25f * (x0.w + t0.w + t1.w + acc.w);
    if (gid < NUSERS) {
        float4 ul = *(const float4*)(ulocal + o);
        r.x += ul.x; r.y += ul.y; r.z += ul.z; r.w += ul.w;
    }
    *(float4*)(out + o) = r;
}

// ---------------------------------------------------------------------------
extern "C" void kernel_launch(void* const* d_in, const int* in_sizes, int n_in,
                              void* d_out, int out_size, void* d_ws, size_t ws_size,
                              hipStream_t stream) {
    const float* user_emb = (const float*)d_in[0];
    const float* item_emb = (const float*)d_in[1];
    const float* adj_val  = (const float*)d_in[2];
    const float* hv_val   = (const float*)d_in[3];
    const float* hu_val   = (const float*)d_in[4];
    const int*   adj_row  = (const int*)d_in[5];
    const int*   adj_col  = (const int*)d_in[6];
    const int*   hv_row   = (const int*)d_in[7];
    const int*   hv_col   = (const int*)d_in[8];
    const int*   hu_row   = (const int*)d_in[9];
    const int*   hu_col   = (const int*)d_in[10];

    const int E_ADJ = in_sizes[2];
    const int E_HV  = in_sizes[3];
    const int E_HU  = in_sizes[4];
    const int E_ALL = E_ADJ + E_HV + E_HU;

    // -------- workspace carve-up (256B-aligned) --------
    char* ws = (char*)d_ws;
    auto alloc = [&](size_t bytes) -> char* {
        char* p = ws;
        ws += (bytes + 255) & ~(size_t)255;
        return p;
    };
    const size_t SZ_NODE = (size_t)NTOT * DIM * sizeof(float);   // 38.4 MB
    float* T0      = (float*)alloc(SZ_NODE);
    float* T1      = (float*)alloc(SZ_NODE);
    float* bic     = (float*)alloc((size_t)NBIC * DIM * sizeof(float));
    float* ulocal  = (float*)alloc((size_t)NUSERS * DIM * sizeof(float));
    int*   cnt     = (int*)alloc((size_t)NROWS_ALL * sizeof(int));
    int*   start   = (int*)alloc((size_t)NROWS_ALL * sizeof(int));
    int*   cursor  = (int*)alloc((size_t)NROWS_ALL * sizeof(int));
    int2*  edges   = (int2*)alloc((size_t)E_ALL * sizeof(int2));
    int*   bsum    = (int*)alloc(SCAN_B * sizeof(int));

    const int BLK = 256;
    auto cdiv = [](int a, int b) { return (a + b - 1) / b; };

    // ---- fused CSR build ----
    hipMemsetAsync(cnt, 0, (size_t)NROWS_ALL * sizeof(int), stream);
    hist_fused<<<cdiv(E_ALL, BLK), BLK, 0, stream>>>(adj_row, hv_row, hu_row,
                                                     cnt, E_ADJ, E_HV, E_HU);
    int nb = cdiv(NROWS_ALL, SCAN_B);
    scan1_kernel<<<nb, SCAN_B, 0, stream>>>(cnt, start, bsum, NROWS_ALL);
    scan2_kernel<<<1, SCAN_B, 0, stream>>>(bsum, nb);
    scan3_kernel<<<cdiv(NROWS_ALL, BLK), BLK, 0, stream>>>(start, cursor, bsum, NROWS_ALL);

    const int BPP = 120;    // blocks per partition; grid = 960 blocks
    scatter_part<<<BPP * NPART, BLK, 0, stream>>>(adj_row, adj_col, adj_val,
                                                  hv_row, hv_col, hv_val,
                                                  hu_row, hu_col, hu_val,
                                                  cursor, edges, E_ADJ, E_HV, E_HU, BPP);

    // rows per 256-thread block in gather kernels
    const int RPB = BLK >> 4;   // 16

    // ---- layer 1: T0 = A * concat(user,item)
    gather_layer1<<<cdiv(NTOT, RPB), BLK, 0, stream>>>(start, cnt, edges,
                                                       user_emb, item_emb, T0);
    // ---- layer 2: T1 = A * T0
    gather_plain<<<cdiv(NTOT, RPB), BLK, 0, stream>>>(start, cnt, edges, T0, T1, NTOT);
    // ---- biclique: bic = normalize(Hv * item_emb)
    gather_norm<<<cdiv(NBIC, RPB), BLK, 0, stream>>>(start + HV_BASE, cnt + HV_BASE, edges,
                                                     item_emb, bic, NBIC);
    // ---- u_local = normalize(Hu * bic)
    gather_norm<<<cdiv(NUSERS, RPB), BLK, 0, stream>>>(start + HU_BASE, cnt + HU_BASE, edges,
                                                       bic, ulocal, NUSERS);
    // ---- layer 3 + epilogue -> out
    gather_final<<<cdiv(NTOT, RPB), BLK, 0, stream>>>(start, cnt, edges,
                                                      T0, T1, user_emb, item_emb,
                                                      ulocal, (float*)d_out);
}

// Round 5
// 510.388 us; speedup vs baseline: 1.0891x; 1.0891x over previous
//
#include <hip/hip_runtime.h>

#define NUSERS 100000
#define NITEMS 50000
#define NTOT   150000   // NUSERS + NITEMS
#define NBIC   20000
#define DIM    64
#define SCAN_B 1024

// concatenated row space: [adj rows | hv rows | hu rows]
#define HV_BASE  NTOT
#define HU_BASE  (NTOT + NBIC)
#define NROWS_ALL (NTOT + NBIC + NUSERS)   // 270000

// bucket sort params
#define NBKT     512
#define CHUNK    8192   // edges per phase-A block
#define EDGE_CAP 4608   // >= Q + max row degree (Q ~= 3907)
#define ROWS_CAP 8192   // max rows per bucket (stat. bound ~1100)

// ---------------------------------------------------------------------------
// histogram -> 2-level exclusive scan (unchanged)
// ---------------------------------------------------------------------------
__global__ void hist_fused(const int* __restrict__ adj_row,
                           const int* __restrict__ hv_row,
                           const int* __restrict__ hu_row,
                           int* __restrict__ cnt,
                           int e_adj, int e_hv, int e_hu) {
    int t = blockIdx.x * blockDim.x + threadIdx.x;
    int r;
    if (t < e_adj)                    r = adj_row[t];
    else if (t < e_adj + e_hv)        r = HV_BASE + hv_row[t - e_adj];
    else if (t < e_adj + e_hv + e_hu) r = HU_BASE + hu_row[t - e_adj - e_hv];
    else return;
    atomicAdd(&cnt[r], 1);
}

__global__ void scan1_kernel(const int* __restrict__ cnt, int* __restrict__ ex,
                             int* __restrict__ bsum, int n) {
    __shared__ int s[SCAN_B];
    int tid = threadIdx.x;
    int g = blockIdx.x * SCAN_B + tid;
    int v = (g < n) ? cnt[g] : 0;
    s[tid] = v;
    __syncthreads();
    for (int off = 1; off < SCAN_B; off <<= 1) {
        int t = (tid >= off) ? s[tid - off] : 0;
        __syncthreads();
        s[tid] += t;
        __syncthreads();
    }
    if (g < n) ex[g] = s[tid] - v;
    if (tid == SCAN_B - 1) bsum[blockIdx.x] = s[tid];
}

__global__ void scan2_kernel(int* __restrict__ bsum, int nb) {
    __shared__ int s[SCAN_B];
    int tid = threadIdx.x;
    int v = (tid < nb) ? bsum[tid] : 0;
    s[tid] = v;
    __syncthreads();
    for (int off = 1; off < SCAN_B; off <<= 1) {
        int t = (tid >= off) ? s[tid - off] : 0;
        __syncthreads();
        s[tid] += t;
        __syncthreads();
    }
    if (tid < nb) bsum[tid] = s[tid] - v;
}

__global__ void scan3_kernel(int* __restrict__ ex, const int* __restrict__ bsum, int n) {
    int g = blockIdx.x * blockDim.x + threadIdx.x;
    if (g < n) ex[g] += bsum[g >> 10];
}

// ---------------------------------------------------------------------------
// Bucket boundaries: B[b] = lower_bound(start, b*Q); init bucket cursors.
// ---------------------------------------------------------------------------
__global__ void bounds_kernel(const int* __restrict__ start, int* __restrict__ B,
                              int* __restrict__ bkt_cursor, int Q, int e_all) {
    int b = blockIdx.x * blockDim.x + threadIdx.x;
    if (b > NBKT) return;
    if (b == NBKT) { B[b] = NROWS_ALL; return; }
    int target = b * Q;
    int lo = 0, hi = NROWS_ALL;
    while (lo < hi) {
        int m = (lo + hi) >> 1;
        if (start[m] < target) lo = m + 1; else hi = m;
    }
    B[b] = lo;
    bkt_cursor[b] = (lo < NROWS_ALL) ? start[lo] : e_all;
}

// rowbucket[r] = largest b with B[b] <= r
__global__ void rowbkt_kernel(const int* __restrict__ B, int* __restrict__ rowbucket) {
    int r = blockIdx.x * blockDim.x + threadIdx.x;
    if (r >= NROWS_ALL) return;
    int lo = 0, hi = NBKT - 1;
    while (lo < hi) {
        int m = (lo + hi + 1) >> 1;
        if (B[m] <= r) lo = m; else hi = m - 1;
    }
    rowbucket[r] = lo;
}

// ---------------------------------------------------------------------------
// Phase A: LDS-binned coarse scatter. Each block stages CHUNK edges sorted by
// bucket in LDS, reserves per-bucket runs globally, flushes contiguous runs.
// tmp.x packs  (rowLocal << 18) | col   (col < 2^18, rowLocal < 2^13).
// ---------------------------------------------------------------------------
__global__ void __launch_bounds__(256)
phaseA_kernel(const int* __restrict__ adj_row, const int* __restrict__ adj_col,
              const float* __restrict__ adj_val,
              const int* __restrict__ hv_row, const int* __restrict__ hv_col,
              const float* __restrict__ hv_val,
              const int* __restrict__ hu_row, const int* __restrict__ hu_col,
              const float* __restrict__ hu_val,
              const int* __restrict__ rowbucket, const int* __restrict__ B,
              int* __restrict__ bkt_cursor, int2* __restrict__ tmp,
              int e_adj, int e_hv, int e_hu) {
    __shared__ int hist[NBKT];     // counts, then local cursor
    __shared__ int lstart[NBKT];   // local exclusive offsets
    __shared__ int destB[NBKT];    // global runbase - lstart
    __shared__ int Bl[NBKT];       // bucket boundary rows
    __shared__ int psum[256];
    __shared__ int2 stage[CHUNK];  // 64 KB

    const int tid = threadIdx.x;
    const int e_all = e_adj + e_hv + e_hu;
    const int base = blockIdx.x * CHUNK;
    const int nloc = min(CHUNK, e_all - base);

    for (int i = tid; i < NBKT; i += 256) { hist[i] = 0; Bl[i] = B[i]; }
    __syncthreads();

    // pass 1: count per bucket
    for (int i = tid; i < nloc; i += 256) {
        int t = base + i, r;
        if (t < e_adj)             r = adj_row[t];
        else if (t < e_adj + e_hv) r = HV_BASE + hv_row[t - e_adj];
        else                       r = HU_BASE + hu_row[t - e_adj - e_hv];
        atomicAdd(&hist[rowbucket[r]], 1);
    }
    __syncthreads();

    // local exclusive scan of hist (2 entries per thread)
    int a0 = hist[2 * tid], a1 = hist[2 * tid + 1];
    psum[tid] = a0 + a1;
    __syncthreads();
    for (int off = 1; off < 256; off <<= 1) {
        int v = (tid >= off) ? psum[tid - off] : 0;
        __syncthreads();
        psum[tid] += v;
        __syncthreads();
    }
    int ex = psum[tid] - (a0 + a1);
    lstart[2 * tid]     = ex;
    lstart[2 * tid + 1] = ex + a0;
    __syncthreads();

    // reserve global runs
    for (int b = tid; b < NBKT; b += 256) {
        int c = hist[b];
        if (c > 0) destB[b] = atomicAdd(&bkt_cursor[b], c) - lstart[b];
    }
    __syncthreads();
    // reuse hist as local cursor
    for (int b = tid; b < NBKT; b += 256) hist[b] = lstart[b];
    __syncthreads();

    // pass 2: stage into LDS, bucket-sorted
    for (int i = tid; i < nloc; i += 256) {
        int t = base + i, r, c; float v;
        if (t < e_adj)             { r = adj_row[t]; c = adj_col[t]; v = adj_val[t]; }
        else if (t < e_adj + e_hv) { int k = t - e_adj;
                                     r = HV_BASE + hv_row[k]; c = hv_col[k]; v = hv_val[k]; }
        else                       { int k = t - e_adj - e_hv;
                                     r = HU_BASE + hu_row[k]; c = hu_col[k]; v = hu_val[k]; }
        int b  = rowbucket[r];
        int rl = r - Bl[b];                       // rowLocal < ROWS_CAP
        int p  = atomicAdd(&hist[b], 1);
        stage[p] = make_int2(c | (rl << 18), __float_as_int(v));
    }
    __syncthreads();

    // flush: wave w handles buckets w, w+4, ... — contiguous run per bucket
    const int wave = tid >> 6, lane = tid & 63;
    for (int b = wave; b < NBKT; b += 4) {
        int s = lstart[b];
        int e = hist[b];                          // cursor end = s + cnt
        int d = destB[b];
        for (int j = s + lane; j < e; j += 64)
            tmp[d + j] = stage[j];
    }
}

// ---------------------------------------------------------------------------
// Phase B: per-bucket LDS counting sort -> final CSR-ordered edges, all
// global reads/writes fully coalesced.
// ---------------------------------------------------------------------------
__global__ void __launch_bounds__(256)
phaseB_kernel(const int* __restrict__ B, const int* __restrict__ start,
              const int2* __restrict__ tmp, int2* __restrict__ edges, int e_all) {
    __shared__ int  cur[ROWS_CAP];    // 32 KB
    __shared__ int2 stage[EDGE_CAP];  // 36.8 KB
    const int tid = threadIdx.x;
    const int b = blockIdx.x;
    const int rlo = B[b], rhi = B[b + 1];
    const int gbase = (rlo < NROWS_ALL) ? start[rlo] : e_all;
    const int gend  = (rhi < NROWS_ALL) ? start[rhi] : e_all;
    const int nE = gend - gbase, nR = rhi - rlo;
    if (nE <= 0) return;

    for (int i = tid; i < nR; i += 256) cur[i] = start[rlo + i] - gbase;
    __syncthreads();
    for (int i = tid; i < nE; i += 256) {
        int2 e = tmp[gbase + i];
        int rl = ((unsigned)e.x) >> 18;
        int p = atomicAdd(&cur[rl], 1);
        stage[p] = make_int2(e.x & 0x3FFFF, e.y);
    }
    __syncthreads();
    for (int i = tid; i < nE; i += 256) edges[gbase + i] = stage[i];
}

// ---------------------------------------------------------------------------
// Gather SpMMs (unchanged from round 3/4)
// ---------------------------------------------------------------------------
__device__ __forceinline__ float4 f4zero() {
    float4 z; z.x = z.y = z.z = z.w = 0.f; return z;
}

__global__ void gather_layer1(const int* __restrict__ start, const int* __restrict__ cnt,
                              const int2* __restrict__ edges,
                              const float* __restrict__ user, const float* __restrict__ item,
                              float* __restrict__ out) {
    int gid = blockIdx.x * (blockDim.x >> 4) + (threadIdx.x >> 4);
    if (gid >= NTOT) return;
    int c = (threadIdx.x & 15) << 2;
    int s = start[gid], n = cnt[gid];
    float4 acc = f4zero();
    for (int j = s; j < s + n; ++j) {
        int2 e = edges[j];
        int cc = e.x;
        float v = __int_as_float(e.y);
        const float* src = (cc < NUSERS) ? user + (size_t)cc * DIM
                                         : item + (size_t)(cc - NUSERS) * DIM;
        float4 xv = *(const float4*)(src + c);
        acc.x += v * xv.x; acc.y += v * xv.y; acc.z += v * xv.z; acc.w += v * xv.w;
    }
    *(float4*)(out + (size_t)gid * DIM + c) = acc;
}

__global__ void gather_plain(const int* __restrict__ start, const int* __restrict__ cnt,
                             const int2* __restrict__ edges,
                             const float* __restrict__ x, float* __restrict__ out, int nrows) {
    int gid = blockIdx.x * (blockDim.x >> 4) + (threadIdx.x >> 4);
    if (gid >= nrows) return;
    int c = (threadIdx.x & 15) << 2;
    int s = start[gid], n = cnt[gid];
    float4 acc = f4zero();
    for (int j = s; j < s + n; ++j) {
        int2 e = edges[j];
        int cc = e.x;
        float v = __int_as_float(e.y);
        float4 xv = *(const float4*)(x + (size_t)cc * DIM + c);
        acc.x += v * xv.x; acc.y += v * xv.y; acc.z += v * xv.z; acc.w += v * xv.w;
    }
    *(float4*)(out + (size_t)gid * DIM + c) = acc;
}

__global__ void gather_norm(const int* __restrict__ start, const int* __restrict__ cnt,
                            const int2* __restrict__ edges,
                            const float* __restrict__ x, float* __restrict__ out, int nrows) {
    int gid = blockIdx.x * (blockDim.x >> 4) + (threadIdx.x >> 4);
    if (gid >= nrows) return;
    int c = (threadIdx.x & 15) << 2;
    int s = start[gid], n = cnt[gid];
    float4 acc = f4zero();
    float deg = 0.f;
    for (int j = s; j < s + n; ++j) {
        int2 e = edges[j];
        int cc = e.x;
        float v = __int_as_float(e.y);
        deg += v;
        float4 xv = *(const float4*)(x + (size_t)cc * DIM + c);
        acc.x += v * xv.x; acc.y += v * xv.y; acc.z += v * xv.z; acc.w += v * xv.w;
    }
    if (deg == 0.f) deg = 1.f;
    float inv = 1.f / deg;
    acc.x *= inv; acc.y *= inv; acc.z *= inv; acc.w *= inv;
    *(float4*)(out + (size_t)gid * DIM + c) = acc;
}

__global__ void gather_final(const int* __restrict__ start, const int* __restrict__ cnt,
                             const int2* __restrict__ edges,
                             const float* __restrict__ T0, const float* __restrict__ T1,
                             const float* __restrict__ user, const float* __restrict__ item,
                             const float* __restrict__ ulocal, float* __restrict__ out) {
    int gid = blockIdx.x * (blockDim.x >> 4) + (threadIdx.x >> 4);
    if (gid >= NTOT) return;
    int c = (threadIdx.x & 15) << 2;
    int s = start[gid], n = cnt[gid];
    float4 acc = f4zero();
    for (int j = s; j < s + n; ++j) {
        int2 e = edges[j];
        int cc = e.x;
        float v = __int_as_float(e.y);
        float4 xv = *(const float4*)(T1 + (size_t)cc * DIM + c);
        acc.x += v * xv.x; acc.y += v * xv.y; acc.z += v * xv.z; acc.w += v * xv.w;
    }
    size_t o = (size_t)gid * DIM + c;
    float4 x0 = (gid < NUSERS) ? *(const float4*)(user + o)
                               : *(const float4*)(item + o - (size_t)NUSERS * DIM);
    float4 t0 = *(const float4*)(T0 + o);
    float4 t1 = *(const float4*)(T1 + o);
    float4 r;
    r.x = 0.25f * (x0.x + t0.x + t1.x + acc.x);
    r.y = 0.25f * (x0.y + t0.y + t1.y + acc.y);
    r.z = 0.25f * (x0.z + t0.z + t1.z + acc.z);
    r.w = 0.25f * (x0.w + t0.w + t1.w + acc.w);
    if (gid < NUSERS) {
        float4 ul = *(const float4*)(ulocal + o);
        r.x += ul.x; r.y += ul.y; r.z += ul.z; r.w += ul.w;
    }
    *(float4*)(out + o) = r;
}

// ---------------------------------------------------------------------------
extern "C" void kernel_launch(void* const* d_in, const int* in_sizes, int n_in,
                              void* d_out, int out_size, void* d_ws, size_t ws_size,
                              hipStream_t stream) {
    const float* user_emb = (const float*)d_in[0];
    const float* item_emb = (const float*)d_in[1];
    const float* adj_val  = (const float*)d_in[2];
    const float* hv_val   = (const float*)d_in[3];
    const float* hu_val   = (const float*)d_in[4];
    const int*   adj_row  = (const int*)d_in[5];
    const int*   adj_col  = (const int*)d_in[6];
    const int*   hv_row   = (const int*)d_in[7];
    const int*   hv_col   = (const int*)d_in[8];
    const int*   hu_row   = (const int*)d_in[9];
    const int*   hu_col   = (const int*)d_in[10];

    const int E_ADJ = in_sizes[2];
    const int E_HV  = in_sizes[3];
    const int E_HU  = in_sizes[4];
    const int E_ALL = E_ADJ + E_HV + E_HU;

    // -------- workspace carve-up (256B-aligned) --------
    char* ws = (char*)d_ws;
    auto alloc = [&](size_t bytes) -> char* {
        char* p = ws;
        ws += (bytes + 255) & ~(size_t)255;
        return p;
    };
    const size_t SZ_NODE = (size_t)NTOT * DIM * sizeof(float);   // 38.4 MB
    float* T0        = (float*)alloc(SZ_NODE);
    float* T1        = (float*)alloc(SZ_NODE);
    float* bic       = (float*)alloc((size_t)NBIC * DIM * sizeof(float));
    float* ulocal    = (float*)alloc((size_t)NUSERS * DIM * sizeof(float));
    int*   cnt       = (int*)alloc((size_t)NROWS_ALL * sizeof(int));
    int*   start     = (int*)alloc((size_t)NROWS_ALL * sizeof(int));
    int*   rowbucket = (int*)alloc((size_t)NROWS_ALL * sizeof(int));
    int2*  edges     = (int2*)alloc((size_t)E_ALL * sizeof(int2));
    int2*  edges_tmp = (int2*)alloc((size_t)E_ALL * sizeof(int2));
    int*   Bnd       = (int*)alloc((NBKT + 1) * sizeof(int));
    int*   bkt_cur   = (int*)alloc(NBKT * sizeof(int));
    int*   bsum      = (int*)alloc(SCAN_B * sizeof(int));

    const int BLK = 256;
    auto cdiv = [](int a, int b) { return (a + b - 1) / b; };

    // ---- histogram + scan -> start[] ----
    hipMemsetAsync(cnt, 0, (size_t)NROWS_ALL * sizeof(int), stream);
    hist_fused<<<cdiv(E_ALL, BLK), BLK, 0, stream>>>(adj_row, hv_row, hu_row,
                                                     cnt, E_ADJ, E_HV, E_HU);
    int nb = cdiv(NROWS_ALL, SCAN_B);
    scan1_kernel<<<nb, SCAN_B, 0, stream>>>(cnt, start, bsum, NROWS_ALL);
    scan2_kernel<<<1, SCAN_B, 0, stream>>>(bsum, nb);
    scan3_kernel<<<cdiv(NROWS_ALL, BLK), BLK, 0, stream>>>(start, bsum, NROWS_ALL);

    // ---- bucket boundaries + row->bucket table ----
    const int Q = cdiv(E_ALL, NBKT);
    bounds_kernel<<<cdiv(NBKT + 1, BLK), BLK, 0, stream>>>(start, Bnd, bkt_cur, Q, E_ALL);
    rowbkt_kernel<<<cdiv(NROWS_ALL, BLK), BLK, 0, stream>>>(Bnd, rowbucket);

    // ---- phase A: coarse bucket scatter (coalesced runs) ----
    phaseA_kernel<<<cdiv(E_ALL, CHUNK), BLK, 0, stream>>>(adj_row, adj_col, adj_val,
                                                          hv_row, hv_col, hv_val,
                                                          hu_row, hu_col, hu_val,
                                                          rowbucket, Bnd, bkt_cur,
                                                          edges_tmp, E_ADJ, E_HV, E_HU);
    // ---- phase B: per-bucket counting sort -> CSR order ----
    phaseB_kernel<<<NBKT, BLK, 0, stream>>>(Bnd, start, edges_tmp, edges, E_ALL);

    // rows per 256-thread block in gather kernels
    const int RPB = BLK >> 4;   // 16

    gather_layer1<<<cdiv(NTOT, RPB), BLK, 0, stream>>>(start, cnt, edges,
                                                       user_emb, item_emb, T0);
    gather_plain<<<cdiv(NTOT, RPB), BLK, 0, stream>>>(start, cnt, edges, T0, T1, NTOT);
    gather_norm<<<cdiv(NBIC, RPB), BLK, 0, stream>>>(start + HV_BASE, cnt + HV_BASE, edges,
                                                     item_emb, bic, NBIC);
    gather_norm<<<cdiv(NUSERS, RPB), BLK, 0, stream>>>(start + HU_BASE, cnt + HU_BASE, edges,
                                                       bic, ulocal, NUSERS);
    gather_final<<<cdiv(NTOT, RPB), BLK, 0, stream>>>(start, cnt, edges,
                                                      T0, T1, user_emb, item_emb,
                                                      ulocal, (float*)d_out);
}

// Round 6
// 413.703 us; speedup vs baseline: 1.3436x; 1.2337x over previous
//
#include <hip/hip_runtime.h>

#define NUSERS 100000
#define NITEMS 50000
#define NTOT   150000   // NUSERS + NITEMS
#define NBIC   20000
#define DIM    64

// concatenated row space: [adj rows | hv rows | hu rows]
#define HV_BASE  NTOT
#define HU_BASE  (NTOT + NBIC)
#define NROWS_ALL (NTOT + NBIC + NUSERS)   // 270000

// static region-aware buckets: ~4000 expected edges per bucket (sigma ~63)
#define ADJ_RPB  500
#define NB_ADJ   300     // 300*500 = 150000
#define HV_RPB   200
#define NB_HV    100     // 100*200 = 20000
#define HU_RPB   1000
#define NB_HU    100     // 100*1000 = 100000
#define NBKT     (NB_ADJ + NB_HV + NB_HU)   // 500
#define HSIZE    512     // hist padded to power-of-2 for the block scan

#define EDGE_CAP 5120    // per-bucket slice capacity (17 sigma over 4000)
#define ROWS_CAP 1024    // max rows per bucket (HU_RPB = 1000)
#define CHUNK    8192    // edges per phase-A block

// bucket id and row-local index from concatenated row id (pure arithmetic)
__device__ __forceinline__ void bucket_of(int r, int& b, int& rl) {
    if (r < NTOT)          { int q = r / ADJ_RPB;               b = q;                rl = r - q * ADJ_RPB; }
    else if (r < HU_BASE)  { int rr = r - HV_BASE; int q = rr / HV_RPB;
                             b = NB_ADJ + q;                    rl = rr - q * HV_RPB; }
    else                   { int rr = r - HU_BASE; int q = rr / HU_RPB;
                             b = NB_ADJ + NB_HV + q;            rl = rr - q * HU_RPB; }
}

// ---------------------------------------------------------------------------
// Phase A: LDS-binned coarse scatter into fixed per-bucket slices of tmp[].
// tmp.x packs  (rowLocal << 18) | col   (col < 2^18, rowLocal < 2^10).
// ---------------------------------------------------------------------------
__global__ void __launch_bounds__(256)
phaseA_kernel(const int* __restrict__ adj_row, const int* __restrict__ adj_col,
              const float* __restrict__ adj_val,
              const int* __restrict__ hv_row, const int* __restrict__ hv_col,
              const float* __restrict__ hv_val,
              const int* __restrict__ hu_row, const int* __restrict__ hu_col,
              const float* __restrict__ hu_val,
              int* __restrict__ bkt_cnt, int2* __restrict__ tmp,
              int e_adj, int e_hv, int e_hu) {
    __shared__ int hist[HSIZE];    // counts, then local cursor
    __shared__ int lstart[HSIZE];  // local exclusive offsets
    __shared__ int destB[HSIZE];   // global slice base - lstart
    __shared__ int psum[256];
    __shared__ int2 stage[CHUNK];  // 64 KB

    const int tid = threadIdx.x;
    const int e_all = e_adj + e_hv + e_hu;
    const int base = blockIdx.x * CHUNK;
    const int nloc = min(CHUNK, e_all - base);

    for (int i = tid; i < HSIZE; i += 256) hist[i] = 0;
    __syncthreads();

    // pass 1: count per bucket
    for (int i = tid; i < nloc; i += 256) {
        int t = base + i, r;
        if (t < e_adj)             r = adj_row[t];
        else if (t < e_adj + e_hv) r = HV_BASE + hv_row[t - e_adj];
        else                       r = HU_BASE + hu_row[t - e_adj - e_hv];
        int b, rl; bucket_of(r, b, rl);
        atomicAdd(&hist[b], 1);
    }
    __syncthreads();

    // local exclusive scan of hist (2 entries per thread, HSIZE = 512)
    int a0 = hist[2 * tid], a1 = hist[2 * tid + 1];
    psum[tid] = a0 + a1;
    __syncthreads();
    for (int off = 1; off < 256; off <<= 1) {
        int v = (tid >= off) ? psum[tid - off] : 0;
        __syncthreads();
        psum[tid] += v;
        __syncthreads();
    }
    int ex = psum[tid] - (a0 + a1);
    lstart[2 * tid]     = ex;
    lstart[2 * tid + 1] = ex + a0;
    __syncthreads();

    // reserve runs inside each bucket's fixed slice
    for (int b = tid; b < NBKT; b += 256) {
        int c = hist[b];
        if (c > 0)
            destB[b] = b * EDGE_CAP + atomicAdd(&bkt_cnt[b], c) - lstart[b];
    }
    __syncthreads();
    for (int b = tid; b < HSIZE; b += 256) hist[b] = lstart[b];  // reuse as cursor
    __syncthreads();

    // pass 2: stage into LDS, bucket-sorted
    for (int i = tid; i < nloc; i += 256) {
        int t = base + i, r, c; float v;
        if (t < e_adj)             { r = adj_row[t]; c = adj_col[t]; v = adj_val[t]; }
        else if (t < e_adj + e_hv) { int k = t - e_adj;
                                     r = HV_BASE + hv_row[k]; c = hv_col[k]; v = hv_val[k]; }
        else                       { int k = t - e_adj - e_hv;
                                     r = HU_BASE + hu_row[k]; c = hu_col[k]; v = hu_val[k]; }
        int b, rl; bucket_of(r, b, rl);
        int p = atomicAdd(&hist[b], 1);
        stage[p] = make_int2(c | (rl << 18), __float_as_int(v));
    }
    __syncthreads();

    // flush: wave w handles buckets w, w+4, ... — contiguous run per bucket
    const int wave = tid >> 6, lane = tid & 63;
    for (int b = wave; b < NBKT; b += 4) {
        int s = lstart[b];
        int e = hist[b];
        int d = destB[b];
        for (int j = s + lane; j < e; j += 64)
            tmp[d + j] = stage[j];
    }
}

// exclusive scan of the 500 bucket counts -> global bucket bases (1 block)
__global__ void bkt_scan(const int* __restrict__ cnt, int* __restrict__ base) {
    __shared__ int s[HSIZE];
    int tid = threadIdx.x;
    int v = (tid < NBKT) ? cnt[tid] : 0;
    s[tid] = v;
    __syncthreads();
    for (int off = 1; off < HSIZE; off <<= 1) {
        int t = (tid >= off) ? s[tid - off] : 0;
        __syncthreads();
        s[tid] += t;
        __syncthreads();
    }
    if (tid < NBKT) base[tid] = s[tid] - v;
}

// ---------------------------------------------------------------------------
// Phase B: per-bucket LDS row-histogram + scan (emits start[]/cnt[]) and
// counting sort -> final CSR-ordered edges. All global traffic coalesced.
// ---------------------------------------------------------------------------
__global__ void __launch_bounds__(256)
phaseB_kernel(const int* __restrict__ bkt_cnt, const int* __restrict__ bkt_base,
              const int2* __restrict__ tmp, int2* __restrict__ edges,
              int* __restrict__ start, int* __restrict__ cntArr) {
    __shared__ int  rh[ROWS_CAP];     // per-row counts
    __shared__ int  rs[ROWS_CAP];     // per-row local start, then cursor
    __shared__ int  psum[256];
    __shared__ int2 stage[EDGE_CAP];  // 40 KB

    const int tid = threadIdx.x;
    const int b = blockIdx.x;
    int rlo, nR;
    if (b < NB_ADJ)              { rlo = b * ADJ_RPB;                          nR = ADJ_RPB; }
    else if (b < NB_ADJ + NB_HV) { rlo = HV_BASE + (b - NB_ADJ) * HV_RPB;      nR = HV_RPB; }
    else                         { rlo = HU_BASE + (b - NB_ADJ - NB_HV) * HU_RPB; nR = HU_RPB; }

    const int nE = bkt_cnt[b];
    const int gbase = bkt_base[b];
    const int2* src = tmp + (size_t)b * EDGE_CAP;

    for (int i = tid; i < ROWS_CAP; i += 256) rh[i] = 0;
    __syncthreads();

    // per-row histogram from staged edges (coalesced reads, LDS atomics)
    for (int i = tid; i < nE; i += 256) {
        int2 e = src[i];
        atomicAdd(&rh[((unsigned)e.x) >> 18], 1);
    }
    __syncthreads();

    // exclusive scan over ROWS_CAP entries, 4 per thread
    int b4 = tid * 4;
    int a0 = rh[b4], a1 = rh[b4 + 1], a2 = rh[b4 + 2], a3 = rh[b4 + 3];
    int tot = a0 + a1 + a2 + a3;
    psum[tid] = tot;
    __syncthreads();
    for (int off = 1; off < 256; off <<= 1) {
        int v = (tid >= off) ? psum[tid - off] : 0;
        __syncthreads();
        psum[tid] += v;
        __syncthreads();
    }
    int ex = psum[tid] - tot;
    rs[b4]     = ex;
    rs[b4 + 1] = ex + a0;
    rs[b4 + 2] = ex + a0 + a1;
    rs[b4 + 3] = ex + a0 + a1 + a2;
    __syncthreads();

    // emit global CSR offsets for this bucket's rows
    for (int i = tid; i < nR; i += 256) {
        start[rlo + i]  = gbase + rs[i];
        cntArr[rlo + i] = rh[i];
    }
    __syncthreads();

    // counting sort into stage (rs doubles as cursor), then coalesced flush
    for (int i = tid; i < nE; i += 256) {
        int2 e = src[i];
        int rl = ((unsigned)e.x) >> 18;
        int p = atomicAdd(&rs[rl], 1);
        stage[p] = make_int2(e.x & 0x3FFFF, e.y);
    }
    __syncthreads();
    for (int i = tid; i < nE; i += 256) edges[gbase + i] = stage[i];
}

// ---------------------------------------------------------------------------
// Gather SpMMs: 16 threads per output row; each thread owns one float4 chunk.
// ---------------------------------------------------------------------------
__device__ __forceinline__ float4 f4zero() {
    float4 z; z.x = z.y = z.z = z.w = 0.f; return z;
}

__global__ void gather_layer1(const int* __restrict__ start, const int* __restrict__ cnt,
                              const int2* __restrict__ edges,
                              const float* __restrict__ user, const float* __restrict__ item,
                              float* __restrict__ out) {
    int gid = blockIdx.x * (blockDim.x >> 4) + (threadIdx.x >> 4);
    if (gid >= NTOT) return;
    int c = (threadIdx.x & 15) << 2;
    int s = start[gid], n = cnt[gid];
    float4 acc = f4zero();
    for (int j = s; j < s + n; ++j) {
        int2 e = edges[j];
        int cc = e.x;
        float v = __int_as_float(e.y);
        const float* src = (cc < NUSERS) ? user + (size_t)cc * DIM
                                         : item + (size_t)(cc - NUSERS) * DIM;
        float4 xv = *(const float4*)(src + c);
        acc.x += v * xv.x; acc.y += v * xv.y; acc.z += v * xv.z; acc.w += v * xv.w;
    }
    *(float4*)(out + (size_t)gid * DIM + c) = acc;
}

__global__ void gather_plain(const int* __restrict__ start, const int* __restrict__ cnt,
                             const int2* __restrict__ edges,
                             const float* __restrict__ x, float* __restrict__ out, int nrows) {
    int gid = blockIdx.x * (blockDim.x >> 4) + (threadIdx.x >> 4);
    if (gid >= nrows) return;
    int c = (threadIdx.x & 15) << 2;
    int s = start[gid], n = cnt[gid];
    float4 acc = f4zero();
    for (int j = s; j < s + n; ++j) {
        int2 e = edges[j];
        int cc = e.x;
        float v = __int_as_float(e.y);
        float4 xv = *(const float4*)(x + (size_t)cc * DIM + c);
        acc.x += v * xv.x; acc.y += v * xv.y; acc.z += v * xv.z; acc.w += v * xv.w;
    }
    *(float4*)(out + (size_t)gid * DIM + c) = acc;
}

__global__ void gather_norm(const int* __restrict__ start, const int* __restrict__ cnt,
                            const int2* __restrict__ edges,
                            const float* __restrict__ x, float* __restrict__ out, int nrows) {
    int gid = blockIdx.x * (blockDim.x >> 4) + (threadIdx.x >> 4);
    if (gid >= nrows) return;
    int c = (threadIdx.x & 15) << 2;
    int s = start[gid], n = cnt[gid];
    float4 acc = f4zero();
    float deg = 0.f;
    for (int j = s; j < s + n; ++j) {
        int2 e = edges[j];
        int cc = e.x;
        float v = __int_as_float(e.y);
        deg += v;
        float4 xv = *(const float4*)(x + (size_t)cc * DIM + c);
        acc.x += v * xv.x; acc.y += v * xv.y; acc.z += v * xv.z; acc.w += v * xv.w;
    }
    if (deg == 0.f) deg = 1.f;
    float inv = 1.f / deg;
    acc.x *= inv; acc.y *= inv; acc.z *= inv; acc.w *= inv;
    *(float4*)(out + (size_t)gid * DIM + c) = acc;
}

__global__ void gather_final(const int* __restrict__ start, const int* __restrict__ cnt,
                             const int2* __restrict__ edges,
                             const float* __restrict__ T0, const float* __restrict__ T1,
                             const float* __restrict__ user, const float* __restrict__ item,
                             const float* __restrict__ ulocal, float* __restrict__ out) {
    int gid = blockIdx.x * (blockDim.x >> 4) + (threadIdx.x >> 4);
    if (gid >= NTOT) return;
    int c = (threadIdx.x & 15) << 2;
    int s = start[gid], n = cnt[gid];
    float4 acc = f4zero();
    for (int j = s; j < s + n; ++j) {
        int2 e = edges[j];
        int cc = e.x;
        float v = __int_as_float(e.y);
        float4 xv = *(const float4*)(T1 + (size_t)cc * DIM + c);
        acc.x += v * xv.x; acc.y += v * xv.y; acc.z += v * xv.z; acc.w += v * xv.w;
    }
    size_t o = (size_t)gid * DIM + c;
    float4 x0 = (gid < NUSERS) ? *(const float4*)(user + o)
                               : *(const float4*)(item + o - (size_t)NUSERS * DIM);
    float4 t0 = *(const float4*)(T0 + o);
    float4 t1 = *(const float4*)(T1 + o);
    float4 r;
    r.x = 0.25f * (x0.x + t0.x + t1.x + acc.x);
    r.y = 0.25f * (x0.y + t0.y + t1.y + acc.y);
    r.z = 0.25f * (x0.z + t0.z + t1.z + acc.z);
    r.w = 0.25f * (x0.w + t0.w + t1.w + acc.w);
    if (gid < NUSERS) {
        float4 ul = *(const float4*)(ulocal + o);
        r.x += ul.x; r.y += ul.y; r.z += ul.z; r.w += ul.w;
    }
    *(float4*)(out + o) = r;
}

// ---------------------------------------------------------------------------
extern "C" void kernel_launch(void* const* d_in, const int* in_sizes, int n_in,
                              void* d_out, int out_size, void* d_ws, size_t ws_size,
                              hipStream_t stream) {
    const float* user_emb = (const float*)d_in[0];
    const float* item_emb = (const float*)d_in[1];
    const float* adj_val  = (const float*)d_in[2];
    const float* hv_val   = (const float*)d_in[3];
    const float* hu_val   = (const float*)d_in[4];
    const int*   adj_row  = (const int*)d_in[5];
    const int*   adj_col  = (const int*)d_in[6];
    const int*   hv_row   = (const int*)d_in[7];
    const int*   hv_col   = (const int*)d_in[8];
    const int*   hu_row   = (const int*)d_in[9];
    const int*   hu_col   = (const int*)d_in[10];

    const int E_ADJ = in_sizes[2];
    const int E_HV  = in_sizes[3];
    const int E_HU  = in_sizes[4];
    const int E_ALL = E_ADJ + E_HV + E_HU;

    // -------- workspace carve-up (256B-aligned) --------
    char* ws = (char*)d_ws;
    auto alloc = [&](size_t bytes) -> char* {
        char* p = ws;
        ws += (bytes + 255) & ~(size_t)255;
        return p;
    };
    const size_t SZ_NODE = (size_t)NTOT * DIM * sizeof(float);   // 38.4 MB
    float* T0       = (float*)alloc(SZ_NODE);
    float* T1       = (float*)alloc(SZ_NODE);
    float* bic      = (float*)alloc((size_t)NBIC * DIM * sizeof(float));
    float* ulocal   = (float*)alloc((size_t)NUSERS * DIM * sizeof(float));
    int*   cnt      = (int*)alloc((size_t)NROWS_ALL * sizeof(int));
    int*   start    = (int*)alloc((size_t)NROWS_ALL * sizeof(int));
    int2*  edges    = (int2*)alloc((size_t)E_ALL * sizeof(int2));
    int2*  tmp      = (int2*)alloc((size_t)NBKT * EDGE_CAP * sizeof(int2));  // 20.5 MB
    int*   bkt_cnt  = (int*)alloc(NBKT * sizeof(int));
    int*   bkt_base = (int*)alloc(NBKT * sizeof(int));

    const int BLK = 256;
    auto cdiv = [](int a, int b) { return (a + b - 1) / b; };

    // ---- CSR build: phase A -> bucket scan -> phase B ----
    hipMemsetAsync(bkt_cnt, 0, NBKT * sizeof(int), stream);
    phaseA_kernel<<<cdiv(E_ALL, CHUNK), BLK, 0, stream>>>(adj_row, adj_col, adj_val,
                                                          hv_row, hv_col, hv_val,
                                                          hu_row, hu_col, hu_val,
                                                          bkt_cnt, tmp, E_ADJ, E_HV, E_HU);
    bkt_scan<<<1, HSIZE, 0, stream>>>(bkt_cnt, bkt_base);
    phaseB_kernel<<<NBKT, BLK, 0, stream>>>(bkt_cnt, bkt_base, tmp, edges, start, cnt);

    // rows per 256-thread block in gather kernels
    const int RPB = BLK >> 4;   // 16

    gather_layer1<<<cdiv(NTOT, RPB), BLK, 0, stream>>>(start, cnt, edges,
                                                       user_emb, item_emb, T0);
    gather_plain<<<cdiv(NTOT, RPB), BLK, 0, stream>>>(start, cnt, edges, T0, T1, NTOT);
    gather_norm<<<cdiv(NBIC, RPB), BLK, 0, stream>>>(start + HV_BASE, cnt + HV_BASE, edges,
                                                     item_emb, bic, NBIC);
    gather_norm<<<cdiv(NUSERS, RPB), BLK, 0, stream>>>(start + HU_BASE, cnt + HU_BASE, edges,
                                                       bic, ulocal, NUSERS);
    gather_final<<<cdiv(NTOT, RPB), BLK, 0, stream>>>(start, cnt, edges,
                                                      T0, T1, user_emb, item_emb,
                                                      ulocal, (float*)d_out);
}

// Round 7
// 342.345 us; speedup vs baseline: 1.6237x; 1.2084x over previous
//
#include <hip/hip_runtime.h>

#define NUSERS 100000
#define NITEMS 50000
#define NTOT   150000   // NUSERS + NITEMS
#define NBIC   20000
#define DIM    64

// concatenated row space: [adj rows | hv rows | hu rows]
#define HV_BASE  NTOT
#define HU_BASE  (NTOT + NBIC)
#define NROWS_ALL (NTOT + NBIC + NUSERS)   // 270000

// static region-aware buckets: ~4000 expected edges per bucket (sigma ~63)
#define ADJ_RPB  500
#define NB_ADJ   300
#define HV_RPB   200
#define NB_HV    100
#define HU_RPB   1000
#define NB_HU    100
#define NBKT     (NB_ADJ + NB_HV + NB_HU)   // 500
#define HSIZE    512

#define EDGE_CAP 5120
#define ROWS_CAP 1024
#define CHUNK    8192

typedef _Float16 h8 __attribute__((ext_vector_type(8)));

// bucket id and row-local index from concatenated row id (pure arithmetic)
__device__ __forceinline__ void bucket_of(int r, int& b, int& rl) {
    if (r < NTOT)          { int q = r / ADJ_RPB;               b = q;                rl = r - q * ADJ_RPB; }
    else if (r < HU_BASE)  { int rr = r - HV_BASE; int q = rr / HV_RPB;
                             b = NB_ADJ + q;                    rl = rr - q * HV_RPB; }
    else                   { int rr = r - HU_BASE; int q = rr / HU_RPB;
                             b = NB_ADJ + NB_HV + q;            rl = rr - q * HU_RPB; }
}

// ---------------------------------------------------------------------------
// fp32 concat(user,item) -> fp16 X16 (sequential, one pass)
// ---------------------------------------------------------------------------
__global__ void to_half_kernel(const float* __restrict__ user,
                               const float* __restrict__ item,
                               _Float16* __restrict__ x16) {
    int i = blockIdx.x * blockDim.x + threadIdx.x;   // 8-elem group
    const int n8 = NTOT * DIM / 8;
    if (i >= n8) return;
    const int u8 = NUSERS * DIM / 8;
    const float4* src = (i < u8) ? (const float4*)user + 2 * (size_t)i
                                 : (const float4*)item + 2 * (size_t)(i - u8);
    float4 a = src[0], b = src[1];
    h8 h;
    h[0] = (_Float16)a.x; h[1] = (_Float16)a.y; h[2] = (_Float16)a.z; h[3] = (_Float16)a.w;
    h[4] = (_Float16)b.x; h[5] = (_Float16)b.y; h[6] = (_Float16)b.z; h[7] = (_Float16)b.w;
    ((h8*)x16)[i] = h;
}

// ---------------------------------------------------------------------------
// Phase A: LDS-binned coarse scatter into fixed per-bucket slices of tmp[].
// tmp.x packs  (rowLocal << 18) | col   (col < 2^18, rowLocal < 2^10).
// ---------------------------------------------------------------------------
__global__ void __launch_bounds__(256)
phaseA_kernel(const int* __restrict__ adj_row, const int* __restrict__ adj_col,
              const float* __restrict__ adj_val,
              const int* __restrict__ hv_row, const int* __restrict__ hv_col,
              const float* __restrict__ hv_val,
              const int* __restrict__ hu_row, const int* __restrict__ hu_col,
              const float* __restrict__ hu_val,
              int* __restrict__ bkt_cnt, int2* __restrict__ tmp,
              int e_adj, int e_hv, int e_hu) {
    __shared__ int hist[HSIZE];
    __shared__ int lstart[HSIZE];
    __shared__ int destB[HSIZE];
    __shared__ int psum[256];
    __shared__ int2 stage[CHUNK];  // 64 KB

    const int tid = threadIdx.x;
    const int e_all = e_adj + e_hv + e_hu;
    const int base = blockIdx.x * CHUNK;
    const int nloc = min(CHUNK, e_all - base);

    for (int i = tid; i < HSIZE; i += 256) hist[i] = 0;
    __syncthreads();

    for (int i = tid; i < nloc; i += 256) {
        int t = base + i, r;
        if (t < e_adj)             r = adj_row[t];
        else if (t < e_adj + e_hv) r = HV_BASE + hv_row[t - e_adj];
        else                       r = HU_BASE + hu_row[t - e_adj - e_hv];
        int b, rl; bucket_of(r, b, rl);
        atomicAdd(&hist[b], 1);
    }
    __syncthreads();

    int a0 = hist[2 * tid], a1 = hist[2 * tid + 1];
    psum[tid] = a0 + a1;
    __syncthreads();
    for (int off = 1; off < 256; off <<= 1) {
        int v = (tid >= off) ? psum[tid - off] : 0;
        __syncthreads();
        psum[tid] += v;
        __syncthreads();
    }
    int ex = psum[tid] - (a0 + a1);
    lstart[2 * tid]     = ex;
    lstart[2 * tid + 1] = ex + a0;
    __syncthreads();

    for (int b = tid; b < NBKT; b += 256) {
        int c = hist[b];
        if (c > 0)
            destB[b] = b * EDGE_CAP + atomicAdd(&bkt_cnt[b], c) - lstart[b];
    }
    __syncthreads();
    for (int b = tid; b < HSIZE; b += 256) hist[b] = lstart[b];
    __syncthreads();

    for (int i = tid; i < nloc; i += 256) {
        int t = base + i, r, c; float v;
        if (t < e_adj)             { r = adj_row[t]; c = adj_col[t]; v = adj_val[t]; }
        else if (t < e_adj + e_hv) { int k = t - e_adj;
                                     r = HV_BASE + hv_row[k]; c = hv_col[k]; v = hv_val[k]; }
        else                       { int k = t - e_adj - e_hv;
                                     r = HU_BASE + hu_row[k]; c = hu_col[k]; v = hu_val[k]; }
        int b, rl; bucket_of(r, b, rl);
        int p = atomicAdd(&hist[b], 1);
        stage[p] = make_int2(c | (rl << 18), __float_as_int(v));
    }
    __syncthreads();

    const int wave = tid >> 6, lane = tid & 63;
    for (int b = wave; b < NBKT; b += 4) {
        int s = lstart[b];
        int e = hist[b];
        int d = destB[b];
        for (int j = s + lane; j < e; j += 64)
            tmp[d + j] = stage[j];
    }
}

// exclusive scan of the 500 bucket counts -> global bucket bases (1 block)
__global__ void bkt_scan(const int* __restrict__ cnt, int* __restrict__ base) {
    __shared__ int s[HSIZE];
    int tid = threadIdx.x;
    int v = (tid < NBKT) ? cnt[tid] : 0;
    s[tid] = v;
    __syncthreads();
    for (int off = 1; off < HSIZE; off <<= 1) {
        int t = (tid >= off) ? s[tid - off] : 0;
        __syncthreads();
        s[tid] += t;
        __syncthreads();
    }
    if (tid < NBKT) base[tid] = s[tid] - v;
}

// ---------------------------------------------------------------------------
// Phase B: per-bucket LDS row-histogram + scan (emits start[]/cnt[]) and
// counting sort -> final CSR-ordered edges.
// ---------------------------------------------------------------------------
__global__ void __launch_bounds__(256)
phaseB_kernel(const int* __restrict__ bkt_cnt, const int* __restrict__ bkt_base,
              const int2* __restrict__ tmp, int2* __restrict__ edges,
              int* __restrict__ start, int* __restrict__ cntArr) {
    __shared__ int  rh[ROWS_CAP];
    __shared__ int  rs[ROWS_CAP];
    __shared__ int  psum[256];
    __shared__ int2 stage[EDGE_CAP];  // 40 KB

    const int tid = threadIdx.x;
    const int b = blockIdx.x;
    int rlo, nR;
    if (b < NB_ADJ)              { rlo = b * ADJ_RPB;                          nR = ADJ_RPB; }
    else if (b < NB_ADJ + NB_HV) { rlo = HV_BASE + (b - NB_ADJ) * HV_RPB;      nR = HV_RPB; }
    else                         { rlo = HU_BASE + (b - NB_ADJ - NB_HV) * HU_RPB; nR = HU_RPB; }

    const int nE = bkt_cnt[b];
    const int gbase = bkt_base[b];
    const int2* src = tmp + (size_t)b * EDGE_CAP;

    for (int i = tid; i < ROWS_CAP; i += 256) rh[i] = 0;
    __syncthreads();

    for (int i = tid; i < nE; i += 256) {
        int2 e = src[i];
        atomicAdd(&rh[((unsigned)e.x) >> 18], 1);
    }
    __syncthreads();

    int b4 = tid * 4;
    int a0 = rh[b4], a1 = rh[b4 + 1], a2 = rh[b4 + 2], a3 = rh[b4 + 3];
    int tot = a0 + a1 + a2 + a3;
    psum[tid] = tot;
    __syncthreads();
    for (int off = 1; off < 256; off <<= 1) {
        int v = (tid >= off) ? psum[tid - off] : 0;
        __syncthreads();
        psum[tid] += v;
        __syncthreads();
    }
    int ex = psum[tid] - tot;
    rs[b4]     = ex;
    rs[b4 + 1] = ex + a0;
    rs[b4 + 2] = ex + a0 + a1;
    rs[b4 + 3] = ex + a0 + a1 + a2;
    __syncthreads();

    for (int i = tid; i < nR; i += 256) {
        start[rlo + i]  = gbase + rs[i];
        cntArr[rlo + i] = rh[i];
    }
    __syncthreads();

    for (int i = tid; i < nE; i += 256) {
        int2 e = src[i];
        int rl = ((unsigned)e.x) >> 18;
        int p = atomicAdd(&rs[rl], 1);
        stage[p] = make_int2(e.x & 0x3FFFF, e.y);
    }
    __syncthreads();
    for (int i = tid; i < nE; i += 256) edges[gbase + i] = stage[i];
}

// ---------------------------------------------------------------------------
// Gather SpMMs: 8 threads per output row; each thread owns 8 halfs (16 B).
// Accumulate fp32, store fp16.
// ---------------------------------------------------------------------------
__global__ void gather_h(const int* __restrict__ start, const int* __restrict__ cnt,
                         const int2* __restrict__ edges,
                         const _Float16* __restrict__ x, _Float16* __restrict__ out,
                         int nrows) {
    int gid = blockIdx.x * (blockDim.x >> 3) + (threadIdx.x >> 3);
    if (gid >= nrows) return;
    int c = (threadIdx.x & 7) << 3;
    int s = start[gid], n = cnt[gid];
    float acc[8] = {0.f, 0.f, 0.f, 0.f, 0.f, 0.f, 0.f, 0.f};
    for (int j = s; j < s + n; ++j) {
        int2 e = edges[j];
        float v = __int_as_float(e.y);
        h8 xv = *(const h8*)(x + (size_t)e.x * DIM + c);
        #pragma unroll
        for (int k = 0; k < 8; ++k) acc[k] += v * (float)xv[k];
    }
    h8 o;
    #pragma unroll
    for (int k = 0; k < 8; ++k) o[k] = (_Float16)acc[k];
    *(h8*)(out + (size_t)gid * DIM + c) = o;
}

// gather + row-degree normalization fused (deg = sum val, 0 -> 1)
__global__ void gather_norm_h(const int* __restrict__ start, const int* __restrict__ cnt,
                              const int2* __restrict__ edges,
                              const _Float16* __restrict__ x, _Float16* __restrict__ out,
                              int nrows) {
    int gid = blockIdx.x * (blockDim.x >> 3) + (threadIdx.x >> 3);
    if (gid >= nrows) return;
    int c = (threadIdx.x & 7) << 3;
    int s = start[gid], n = cnt[gid];
    float acc[8] = {0.f, 0.f, 0.f, 0.f, 0.f, 0.f, 0.f, 0.f};
    float deg = 0.f;
    for (int j = s; j < s + n; ++j) {
        int2 e = edges[j];
        float v = __int_as_float(e.y);
        deg += v;
        h8 xv = *(const h8*)(x + (size_t)e.x * DIM + c);
        #pragma unroll
        for (int k = 0; k < 8; ++k) acc[k] += v * (float)xv[k];
    }
    if (deg == 0.f) deg = 1.f;
    float inv = 1.f / deg;
    h8 o;
    #pragma unroll
    for (int k = 0; k < 8; ++k) o[k] = (_Float16)(acc[k] * inv);
    *(h8*)(out + (size_t)gid * DIM + c) = o;
}

// layer 3 + epilogue: out = 0.25*(x0 + t0 + t1 + gather(T1)) [+ ulocal users]
__global__ void gather_final_h(const int* __restrict__ start, const int* __restrict__ cnt,
                               const int2* __restrict__ edges,
                               const _Float16* __restrict__ X16,
                               const _Float16* __restrict__ T0,
                               const _Float16* __restrict__ T1,
                               const _Float16* __restrict__ ulocal,
                               float* __restrict__ out) {
    int gid = blockIdx.x * (blockDim.x >> 3) + (threadIdx.x >> 3);
    if (gid >= NTOT) return;
    int c = (threadIdx.x & 7) << 3;
    int s = start[gid], n = cnt[gid];
    float acc[8] = {0.f, 0.f, 0.f, 0.f, 0.f, 0.f, 0.f, 0.f};
    for (int j = s; j < s + n; ++j) {
        int2 e = edges[j];
        float v = __int_as_float(e.y);
        h8 xv = *(const h8*)(T1 + (size_t)e.x * DIM + c);
        #pragma unroll
        for (int k = 0; k < 8; ++k) acc[k] += v * (float)xv[k];
    }
    size_t o = (size_t)gid * DIM + c;
    h8 x0 = *(const h8*)(X16 + o);
    h8 t0 = *(const h8*)(T0 + o);
    h8 t1 = *(const h8*)(T1 + o);
    float r[8];
    #pragma unroll
    for (int k = 0; k < 8; ++k)
        r[k] = 0.25f * ((float)x0[k] + (float)t0[k] + (float)t1[k] + acc[k]);
    if (gid < NUSERS) {
        h8 ul = *(const h8*)(ulocal + o);
        #pragma unroll
        for (int k = 0; k < 8; ++k) r[k] += (float)ul[k];
    }
    float4 lo = make_float4(r[0], r[1], r[2], r[3]);
    float4 hi = make_float4(r[4], r[5], r[6], r[7]);
    float4* op = (float4*)(out + o);
    op[0] = lo;
    op[1] = hi;
}

// ---------------------------------------------------------------------------
extern "C" void kernel_launch(void* const* d_in, const int* in_sizes, int n_in,
                              void* d_out, int out_size, void* d_ws, size_t ws_size,
                              hipStream_t stream) {
    const float* user_emb = (const float*)d_in[0];
    const float* item_emb = (const float*)d_in[1];
    const float* adj_val  = (const float*)d_in[2];
    const float* hv_val   = (const float*)d_in[3];
    const float* hu_val   = (const float*)d_in[4];
    const int*   adj_row  = (const int*)d_in[5];
    const int*   adj_col  = (const int*)d_in[6];
    const int*   hv_row   = (const int*)d_in[7];
    const int*   hv_col   = (const int*)d_in[8];
    const int*   hu_row   = (const int*)d_in[9];
    const int*   hu_col   = (const int*)d_in[10];

    const int E_ADJ = in_sizes[2];
    const int E_HV  = in_sizes[3];
    const int E_HU  = in_sizes[4];
    const int E_ALL = E_ADJ + E_HV + E_HU;

    // -------- workspace carve-up (256B-aligned) --------
    char* ws = (char*)d_ws;
    auto alloc = [&](size_t bytes) -> char* {
        char* p = ws;
        ws += (bytes + 255) & ~(size_t)255;
        return p;
    };
    const size_t SZ_H = (size_t)NTOT * DIM * sizeof(_Float16);   // 19.2 MB
    _Float16* X16     = (_Float16*)alloc(SZ_H);
    _Float16* T0      = (_Float16*)alloc(SZ_H);
    _Float16* T1      = (_Float16*)alloc(SZ_H);
    _Float16* bic     = (_Float16*)alloc((size_t)NBIC * DIM * sizeof(_Float16));
    _Float16* ulocal  = (_Float16*)alloc((size_t)NUSERS * DIM * sizeof(_Float16));
    int*   cnt      = (int*)alloc((size_t)NROWS_ALL * sizeof(int));
    int*   start    = (int*)alloc((size_t)NROWS_ALL * sizeof(int));
    int2*  edges    = (int2*)alloc((size_t)E_ALL * sizeof(int2));
    int2*  tmp      = (int2*)alloc((size_t)NBKT * EDGE_CAP * sizeof(int2));  // 20.5 MB
    int*   bkt_cnt  = (int*)alloc(NBKT * sizeof(int));
    int*   bkt_base = (int*)alloc(NBKT * sizeof(int));

    const int BLK = 256;
    auto cdiv = [](int a, int b) { return (a + b - 1) / b; };

    // ---- CSR build: phase A -> bucket scan -> phase B ----
    hipMemsetAsync(bkt_cnt, 0, NBKT * sizeof(int), stream);
    phaseA_kernel<<<cdiv(E_ALL, CHUNK), BLK, 0, stream>>>(adj_row, adj_col, adj_val,
                                                          hv_row, hv_col, hv_val,
                                                          hu_row, hu_col, hu_val,
                                                          bkt_cnt, tmp, E_ADJ, E_HV, E_HU);
    // fp32 -> fp16 conversion overlaps nothing but is independent of CSR build
    to_half_kernel<<<cdiv(NTOT * DIM / 8, BLK), BLK, 0, stream>>>(user_emb, item_emb, X16);
    bkt_scan<<<1, HSIZE, 0, stream>>>(bkt_cnt, bkt_base);
    phaseB_kernel<<<NBKT, BLK, 0, stream>>>(bkt_cnt, bkt_base, tmp, edges, start, cnt);

    // rows per 256-thread block in gather kernels (8 lanes/row)
    const int RPB = BLK >> 3;   // 32

    // layer 1: T0 = A * X16
    gather_h<<<cdiv(NTOT, RPB), BLK, 0, stream>>>(start, cnt, edges, X16, T0, NTOT);
    // layer 2: T1 = A * T0
    gather_h<<<cdiv(NTOT, RPB), BLK, 0, stream>>>(start, cnt, edges, T0, T1, NTOT);
    // biclique: bic = normalize(Hv * item16)
    gather_norm_h<<<cdiv(NBIC, RPB), BLK, 0, stream>>>(start + HV_BASE, cnt + HV_BASE, edges,
                                                       X16 + (size_t)NUSERS * DIM, bic, NBIC);
    // u_local = normalize(Hu * bic)
    gather_norm_h<<<cdiv(NUSERS, RPB), BLK, 0, stream>>>(start + HU_BASE, cnt + HU_BASE, edges,
                                                         bic, ulocal, NUSERS);
    // layer 3 + epilogue -> out (fp32)
    gather_final_h<<<cdiv(NTOT, RPB), BLK, 0, stream>>>(start, cnt, edges,
                                                        X16, T0, T1, ulocal, (float*)d_out);
}

// Round 8
// 301.708 us; speedup vs baseline: 1.8424x; 1.1347x over previous
//
#include <hip/hip_runtime.h>

#define NUSERS 100000
#define NITEMS 50000
#define NTOT   150000   // NUSERS + NITEMS
#define NBIC   20000
#define DIM    64

// concatenated row space: [adj rows | hv rows | hu rows]
#define HV_BASE  NTOT
#define HU_BASE  (NTOT + NBIC)
#define NROWS_ALL (NTOT + NBIC + NUSERS)   // 270000

// static region-aware buckets: ~4000 expected edges per bucket (sigma ~63)
#define ADJ_RPB  500
#define NB_ADJ   300
#define HV_RPB   200
#define NB_HV    100
#define HU_RPB   1000
#define NB_HU    100
#define NBKT     (NB_ADJ + NB_HV + NB_HU)   // 500
#define HSIZE    512

#define EDGE_CAP 5120
#define ROWS_CAP 1024
#define CHUNK    8192
#define PA_BLK   1024   // phase-A block size (16 waves/CU)
#define PB_BLK   512    // phase-B block size

typedef _Float16 h8 __attribute__((ext_vector_type(8)));

// bucket id and row-local index from concatenated row id (pure arithmetic)
__device__ __forceinline__ void bucket_of(int r, int& b, int& rl) {
    if (r < NTOT)          { int q = r / ADJ_RPB;               b = q;                rl = r - q * ADJ_RPB; }
    else if (r < HU_BASE)  { int rr = r - HV_BASE; int q = rr / HV_RPB;
                             b = NB_ADJ + q;                    rl = rr - q * HV_RPB; }
    else                   { int rr = r - HU_BASE; int q = rr / HU_RPB;
                             b = NB_ADJ + NB_HV + q;            rl = rr - q * HU_RPB; }
}

// ---------------------------------------------------------------------------
// fp32 concat(user,item) -> fp16 X16 (sequential, one pass)
// ---------------------------------------------------------------------------
__global__ void to_half_kernel(const float* __restrict__ user,
                               const float* __restrict__ item,
                               _Float16* __restrict__ x16) {
    int i = blockIdx.x * blockDim.x + threadIdx.x;   // 8-elem group
    const int n8 = NTOT * DIM / 8;
    if (i >= n8) return;
    const int u8 = NUSERS * DIM / 8;
    const float4* src = (i < u8) ? (const float4*)user + 2 * (size_t)i
                                 : (const float4*)item + 2 * (size_t)(i - u8);
    float4 a = src[0], b = src[1];
    h8 h;
    h[0] = (_Float16)a.x; h[1] = (_Float16)a.y; h[2] = (_Float16)a.z; h[3] = (_Float16)a.w;
    h[4] = (_Float16)b.x; h[5] = (_Float16)b.y; h[6] = (_Float16)b.z; h[7] = (_Float16)b.w;
    ((h8*)x16)[i] = h;
}

// ---------------------------------------------------------------------------
// Phase A: LDS-binned coarse scatter into fixed per-bucket slices of tmp[].
// tmp.x packs  (rowLocal << 18) | col   (col < 2^18, rowLocal < 2^10).
// 1024 threads/block: grid is capped at E_ALL/CHUNK = 245 blocks (< 1/CU),
// so per-block wave count is the only occupancy lever.
// ---------------------------------------------------------------------------
__global__ void __launch_bounds__(PA_BLK)
phaseA_kernel(const int* __restrict__ adj_row, const int* __restrict__ adj_col,
              const float* __restrict__ adj_val,
              const int* __restrict__ hv_row, const int* __restrict__ hv_col,
              const float* __restrict__ hv_val,
              const int* __restrict__ hu_row, const int* __restrict__ hu_col,
              const float* __restrict__ hu_val,
              int* __restrict__ bkt_cnt, int2* __restrict__ tmp,
              int e_adj, int e_hv, int e_hu) {
    __shared__ int hist[HSIZE];
    __shared__ int lstart[HSIZE];
    __shared__ int destB[HSIZE];
    __shared__ int psum[HSIZE];
    __shared__ int2 stage[CHUNK];  // 64 KB

    const int tid = threadIdx.x;
    const int e_all = e_adj + e_hv + e_hu;
    const int base = blockIdx.x * CHUNK;
    const int nloc = min(CHUNK, e_all - base);

    if (tid < HSIZE) hist[tid] = 0;
    __syncthreads();

    // pass 1: count per bucket
    for (int i = tid; i < nloc; i += PA_BLK) {
        int t = base + i, r;
        if (t < e_adj)             r = adj_row[t];
        else if (t < e_adj + e_hv) r = HV_BASE + hv_row[t - e_adj];
        else                       r = HU_BASE + hu_row[t - e_adj - e_hv];
        int b, rl; bucket_of(r, b, rl);
        atomicAdd(&hist[b], 1);
    }
    __syncthreads();

    // exclusive scan over HSIZE=512 entries (threads 0..511 active)
    int v = 0;
    if (tid < HSIZE) { v = hist[tid]; psum[tid] = v; }
    __syncthreads();
    for (int off = 1; off < HSIZE; off <<= 1) {
        int t = 0;
        if (tid < HSIZE && tid >= off) t = psum[tid - off];
        __syncthreads();
        if (tid < HSIZE) psum[tid] += t;
        __syncthreads();
    }
    if (tid < HSIZE) lstart[tid] = psum[tid] - v;
    __syncthreads();

    // reserve runs inside each bucket's fixed slice
    if (tid < NBKT) {
        int c = hist[tid];
        if (c > 0)
            destB[tid] = tid * EDGE_CAP + atomicAdd(&bkt_cnt[tid], c) - lstart[tid];
    }
    __syncthreads();
    if (tid < HSIZE) hist[tid] = lstart[tid];   // reuse as cursor
    __syncthreads();

    // pass 2: stage into LDS, bucket-sorted
    for (int i = tid; i < nloc; i += PA_BLK) {
        int t = base + i, r, c; float v2;
        if (t < e_adj)             { r = adj_row[t]; c = adj_col[t]; v2 = adj_val[t]; }
        else if (t < e_adj + e_hv) { int k = t - e_adj;
                                     r = HV_BASE + hv_row[k]; c = hv_col[k]; v2 = hv_val[k]; }
        else                       { int k = t - e_adj - e_hv;
                                     r = HU_BASE + hu_row[k]; c = hu_col[k]; v2 = hu_val[k]; }
        int b, rl; bucket_of(r, b, rl);
        int p = atomicAdd(&hist[b], 1);
        stage[p] = make_int2(c | (rl << 18), __float_as_int(v2));
    }
    __syncthreads();

    // flush: wave w handles buckets w, w+16, ... — contiguous run per bucket
    const int wave = tid >> 6, lane = tid & 63;
    for (int b = wave; b < NBKT; b += (PA_BLK / 64)) {
        int s = lstart[b];
        int e = hist[b];
        int d = destB[b];
        for (int j = s + lane; j < e; j += 64)
            tmp[d + j] = stage[j];
    }
}

// exclusive scan of the 500 bucket counts -> global bucket bases (1 block)
__global__ void bkt_scan(const int* __restrict__ cnt, int* __restrict__ base) {
    __shared__ int s[HSIZE];
    int tid = threadIdx.x;
    int v = (tid < NBKT) ? cnt[tid] : 0;
    s[tid] = v;
    __syncthreads();
    for (int off = 1; off < HSIZE; off <<= 1) {
        int t = (tid >= off) ? s[tid - off] : 0;
        __syncthreads();
        s[tid] += t;
        __syncthreads();
    }
    if (tid < NBKT) base[tid] = s[tid] - v;
}

// ---------------------------------------------------------------------------
// Phase B: per-bucket LDS row-histogram + scan (emits start[]/cnt[]) and
// counting sort -> final CSR-ordered edges. 512 threads/block.
// ---------------------------------------------------------------------------
__global__ void __launch_bounds__(PB_BLK)
phaseB_kernel(const int* __restrict__ bkt_cnt, const int* __restrict__ bkt_base,
              const int2* __restrict__ tmp, int2* __restrict__ edges,
              int* __restrict__ start, int* __restrict__ cntArr) {
    __shared__ int  rh[ROWS_CAP];
    __shared__ int  rs[ROWS_CAP];
    __shared__ int  psum[PB_BLK];
    __shared__ int2 stage[EDGE_CAP];  // 40 KB

    const int tid = threadIdx.x;
    const int b = blockIdx.x;
    int rlo, nR;
    if (b < NB_ADJ)              { rlo = b * ADJ_RPB;                          nR = ADJ_RPB; }
    else if (b < NB_ADJ + NB_HV) { rlo = HV_BASE + (b - NB_ADJ) * HV_RPB;      nR = HV_RPB; }
    else                         { rlo = HU_BASE + (b - NB_ADJ - NB_HV) * HU_RPB; nR = HU_RPB; }

    const int nE = bkt_cnt[b];
    const int gbase = bkt_base[b];
    const int2* src = tmp + (size_t)b * EDGE_CAP;

    rh[tid] = 0;
    rh[tid + PB_BLK] = 0;
    __syncthreads();

    for (int i = tid; i < nE; i += PB_BLK) {
        int2 e = src[i];
        atomicAdd(&rh[((unsigned)e.x) >> 18], 1);
    }
    __syncthreads();

    // exclusive scan over ROWS_CAP=1024 entries, 2 per thread
    int a0 = rh[2 * tid], a1 = rh[2 * tid + 1];
    int tot = a0 + a1;
    psum[tid] = tot;
    __syncthreads();
    for (int off = 1; off < PB_BLK; off <<= 1) {
        int v = (tid >= off) ? psum[tid - off] : 0;
        __syncthreads();
        psum[tid] += v;
        __syncthreads();
    }
    int ex = psum[tid] - tot;
    rs[2 * tid]     = ex;
    rs[2 * tid + 1] = ex + a0;
    __syncthreads();

    // emit global CSR offsets for this bucket's rows
    for (int i = tid; i < nR; i += PB_BLK) {
        start[rlo + i]  = gbase + rs[i];
        cntArr[rlo + i] = rh[i];
    }
    __syncthreads();

    // counting sort into stage (rs doubles as cursor), then coalesced flush
    for (int i = tid; i < nE; i += PB_BLK) {
        int2 e = src[i];
        int rl = ((unsigned)e.x) >> 18;
        int p = atomicAdd(&rs[rl], 1);
        stage[p] = make_int2(e.x & 0x3FFFF, e.y);
    }
    __syncthreads();
    for (int i = tid; i < nE; i += PB_BLK) edges[gbase + i] = stage[i];
}

// ---------------------------------------------------------------------------
// Gather SpMMs: 8 threads per output row; each thread owns 8 halfs (16 B).
// Accumulate fp32, store fp16.
// ---------------------------------------------------------------------------
__global__ void gather_h(const int* __restrict__ start, const int* __restrict__ cnt,
                         const int2* __restrict__ edges,
                         const _Float16* __restrict__ x, _Float16* __restrict__ out,
                         int nrows) {
    int gid = blockIdx.x * (blockDim.x >> 3) + (threadIdx.x >> 3);
    if (gid >= nrows) return;
    int c = (threadIdx.x & 7) << 3;
    int s = start[gid], n = cnt[gid];
    float acc[8] = {0.f, 0.f, 0.f, 0.f, 0.f, 0.f, 0.f, 0.f};
    for (int j = s; j < s + n; ++j) {
        int2 e = edges[j];
        float v = __int_as_float(e.y);
        h8 xv = *(const h8*)(x + (size_t)e.x * DIM + c);
        #pragma unroll
        for (int k = 0; k < 8; ++k) acc[k] += v * (float)xv[k];
    }
    h8 o;
    #pragma unroll
    for (int k = 0; k < 8; ++k) o[k] = (_Float16)acc[k];
    *(h8*)(out + (size_t)gid * DIM + c) = o;
}

// gather + row-degree normalization fused (deg = sum val, 0 -> 1)
__global__ void gather_norm_h(const int* __restrict__ start, const int* __restrict__ cnt,
                              const int2* __restrict__ edges,
                              const _Float16* __restrict__ x, _Float16* __restrict__ out,
                              int nrows) {
    int gid = blockIdx.x * (blockDim.x >> 3) + (threadIdx.x >> 3);
    if (gid >= nrows) return;
    int c = (threadIdx.x & 7) << 3;
    int s = start[gid], n = cnt[gid];
    float acc[8] = {0.f, 0.f, 0.f, 0.f, 0.f, 0.f, 0.f, 0.f};
    float deg = 0.f;
    for (int j = s; j < s + n; ++j) {
        int2 e = edges[j];
        float v = __int_as_float(e.y);
        deg += v;
        h8 xv = *(const h8*)(x + (size_t)e.x * DIM + c);
        #pragma unroll
        for (int k = 0; k < 8; ++k) acc[k] += v * (float)xv[k];
    }
    if (deg == 0.f) deg = 1.f;
    float inv = 1.f / deg;
    h8 o;
    #pragma unroll
    for (int k = 0; k < 8; ++k) o[k] = (_Float16)(acc[k] * inv);
    *(h8*)(out + (size_t)gid * DIM + c) = o;
}

// layer 3 + epilogue: out = 0.25*(x0 + t0 + t1 + gather(T1)) [+ ulocal users]
__global__ void gather_final_h(const int* __restrict__ start, const int* __restrict__ cnt,
                               const int2* __restrict__ edges,
                               const _Float16* __restrict__ X16,
                               const _Float16* __restrict__ T0,
                               const _Float16* __restrict__ T1,
                               const _Float16* __restrict__ ulocal,
                               float* __restrict__ out) {
    int gid = blockIdx.x * (blockDim.x >> 3) + (threadIdx.x >> 3);
    if (gid >= NTOT) return;
    int c = (threadIdx.x & 7) << 3;
    int s = start[gid], n = cnt[gid];
    float acc[8] = {0.f, 0.f, 0.f, 0.f, 0.f, 0.f, 0.f, 0.f};
    for (int j = s; j < s + n; ++j) {
        int2 e = edges[j];
        float v = __int_as_float(e.y);
        h8 xv = *(const h8*)(T1 + (size_t)e.x * DIM + c);
        #pragma unroll
        for (int k = 0; k < 8; ++k) acc[k] += v * (float)xv[k];
    }
    size_t o = (size_t)gid * DIM + c;
    h8 x0 = *(const h8*)(X16 + o);
    h8 t0 = *(const h8*)(T0 + o);
    h8 t1 = *(const h8*)(T1 + o);
    float r[8];
    #pragma unroll
    for (int k = 0; k < 8; ++k)
        r[k] = 0.25f * ((float)x0[k] + (float)t0[k] + (float)t1[k] + acc[k]);
    if (gid < NUSERS) {
        h8 ul = *(const h8*)(ulocal + o);
        #pragma unroll
        for (int k = 0; k < 8; ++k) r[k] += (float)ul[k];
    }
    float4 lo = make_float4(r[0], r[1], r[2], r[3]);
    float4 hi = make_float4(r[4], r[5], r[6], r[7]);
    float4* op = (float4*)(out + o);
    op[0] = lo;
    op[1] = hi;
}

// ---------------------------------------------------------------------------
extern "C" void kernel_launch(void* const* d_in, const int* in_sizes, int n_in,
                              void* d_out, int out_size, void* d_ws, size_t ws_size,
                              hipStream_t stream) {
    const float* user_emb = (const float*)d_in[0];
    const float* item_emb = (const float*)d_in[1];
    const float* adj_val  = (const float*)d_in[2];
    const float* hv_val   = (const float*)d_in[3];
    const float* hu_val   = (const float*)d_in[4];
    const int*   adj_row  = (const int*)d_in[5];
    const int*   adj_col  = (const int*)d_in[6];
    const int*   hv_row   = (const int*)d_in[7];
    const int*   hv_col   = (const int*)d_in[8];
    const int*   hu_row   = (const int*)d_in[9];
    const int*   hu_col   = (const int*)d_in[10];

    const int E_ADJ = in_sizes[2];
    const int E_HV  = in_sizes[3];
    const int E_HU  = in_sizes[4];
    const int E_ALL = E_ADJ + E_HV + E_HU;

    // -------- workspace carve-up (256B-aligned) --------
    char* ws = (char*)d_ws;
    auto alloc = [&](size_t bytes) -> char* {
        char* p = ws;
        ws += (bytes + 255) & ~(size_t)255;
        return p;
    };
    const size_t SZ_H = (size_t)NTOT * DIM * sizeof(_Float16);   // 19.2 MB
    _Float16* X16     = (_Float16*)alloc(SZ_H);
    _Float16* T0      = (_Float16*)alloc(SZ_H);
    _Float16* T1      = (_Float16*)alloc(SZ_H);
    _Float16* bic     = (_Float16*)alloc((size_t)NBIC * DIM * sizeof(_Float16));
    _Float16* ulocal  = (_Float16*)alloc((size_t)NUSERS * DIM * sizeof(_Float16));
    int*   cnt      = (int*)alloc((size_t)NROWS_ALL * sizeof(int));
    int*   start    = (int*)alloc((size_t)NROWS_ALL * sizeof(int));
    int2*  edges    = (int2*)alloc((size_t)E_ALL * sizeof(int2));
    int2*  tmp      = (int2*)alloc((size_t)NBKT * EDGE_CAP * sizeof(int2));  // 20.5 MB
    int*   bkt_cnt  = (int*)alloc(NBKT * sizeof(int));
    int*   bkt_base = (int*)alloc(NBKT * sizeof(int));

    const int BLK = 256;
    auto cdiv = [](int a, int b) { return (a + b - 1) / b; };

    // ---- CSR build: phase A -> bucket scan -> phase B ----
    hipMemsetAsync(bkt_cnt, 0, NBKT * sizeof(int), stream);
    phaseA_kernel<<<cdiv(E_ALL, CHUNK), PA_BLK, 0, stream>>>(adj_row, adj_col, adj_val,
                                                             hv_row, hv_col, hv_val,
                                                             hu_row, hu_col, hu_val,
                                                             bkt_cnt, tmp, E_ADJ, E_HV, E_HU);
    to_half_kernel<<<cdiv(NTOT * DIM / 8, BLK), BLK, 0, stream>>>(user_emb, item_emb, X16);
    bkt_scan<<<1, HSIZE, 0, stream>>>(bkt_cnt, bkt_base);
    phaseB_kernel<<<NBKT, PB_BLK, 0, stream>>>(bkt_cnt, bkt_base, tmp, edges, start, cnt);

    // rows per 256-thread block in gather kernels (8 lanes/row)
    const int RPB = BLK >> 3;   // 32

    // layer 1: T0 = A * X16
    gather_h<<<cdiv(NTOT, RPB), BLK, 0, stream>>>(start, cnt, edges, X16, T0, NTOT);
    // layer 2: T1 = A * T0
    gather_h<<<cdiv(NTOT, RPB), BLK, 0, stream>>>(start, cnt, edges, T0, T1, NTOT);
    // biclique: bic = normalize(Hv * item16)
    gather_norm_h<<<cdiv(NBIC, RPB), BLK, 0, stream>>>(start + HV_BASE, cnt + HV_BASE, edges,
                                                       X16 + (size_t)NUSERS * DIM, bic, NBIC);
    // u_local = normalize(Hu * bic)
    gather_norm_h<<<cdiv(NUSERS, RPB), BLK, 0, stream>>>(start + HU_BASE, cnt + HU_BASE, edges,
                                                         bic, ulocal, NUSERS);
    // layer 3 + epilogue -> out (fp32)
    gather_final_h<<<cdiv(NTOT, RPB), BLK, 0, stream>>>(start, cnt, edges,
                                                        X16, T0, T1, ulocal, (float*)d_out);
}

// Round 9
// 276.212 us; speedup vs baseline: 2.0124x; 1.0923x over previous
//
#include <hip/hip_runtime.h>

#define NUSERS 100000
#define NITEMS 50000
#define NTOT   150000   // NUSERS + NITEMS
#define NBIC   20000
#define DIM    64

// concatenated row space: [adj rows | hv rows | hu rows]
#define HV_BASE  NTOT
#define HU_BASE  (NTOT + NBIC)
#define NROWS_ALL (NTOT + NBIC + NUSERS)   // 270000

// static region-aware buckets: ~4000 expected edges per bucket
#define ADJ_RPB  500
#define NB_ADJ   300
#define HV_RPB   200
#define NB_HV    100
#define HU_RPB   1000
#define NB_HU    100
#define NBKT     (NB_ADJ + NB_HV + NB_HU)   // 500
#define HSIZE    512

#define EDGE_CAP 5120
#define ROWS_CAP 1024
#define NCLS     64      // degree classes for row permutation
#define CHUNK    8192
#define PA_BLK   1024
#define PB_BLK   512

typedef _Float16 h8 __attribute__((ext_vector_type(8)));

__device__ __forceinline__ void bucket_of(int r, int& b, int& rl) {
    if (r < NTOT)          { int q = r / ADJ_RPB;               b = q;                rl = r - q * ADJ_RPB; }
    else if (r < HU_BASE)  { int rr = r - HV_BASE; int q = rr / HV_RPB;
                             b = NB_ADJ + q;                    rl = rr - q * HV_RPB; }
    else                   { int rr = r - HU_BASE; int q = rr / HU_RPB;
                             b = NB_ADJ + NB_HV + q;            rl = rr - q * HU_RPB; }
}

// ---------------------------------------------------------------------------
__global__ void to_half_kernel(const float* __restrict__ user,
                               const float* __restrict__ item,
                               _Float16* __restrict__ x16) {
    int i = blockIdx.x * blockDim.x + threadIdx.x;   // 8-elem group
    const int n8 = NTOT * DIM / 8;
    if (i >= n8) return;
    const int u8 = NUSERS * DIM / 8;
    const float4* src = (i < u8) ? (const float4*)user + 2 * (size_t)i
                                 : (const float4*)item + 2 * (size_t)(i - u8);
    float4 a = src[0], b = src[1];
    h8 h;
    h[0] = (_Float16)a.x; h[1] = (_Float16)a.y; h[2] = (_Float16)a.z; h[3] = (_Float16)a.w;
    h[4] = (_Float16)b.x; h[5] = (_Float16)b.y; h[6] = (_Float16)b.z; h[7] = (_Float16)b.w;
    ((h8*)x16)[i] = h;
}

// ---------------------------------------------------------------------------
// Phase A: LDS-binned coarse scatter into fixed per-bucket slices of tmp[].
// tmp.x packs (rowLocal << 18) | col.
// ---------------------------------------------------------------------------
__global__ void __launch_bounds__(PA_BLK)
phaseA_kernel(const int* __restrict__ adj_row, const int* __restrict__ adj_col,
              const float* __restrict__ adj_val,
              const int* __restrict__ hv_row, const int* __restrict__ hv_col,
              const float* __restrict__ hv_val,
              const int* __restrict__ hu_row, const int* __restrict__ hu_col,
              const float* __restrict__ hu_val,
              int* __restrict__ bkt_cnt, int2* __restrict__ tmp,
              int e_adj, int e_hv, int e_hu) {
    __shared__ int hist[HSIZE];
    __shared__ int lstart[HSIZE];
    __shared__ int destB[HSIZE];
    __shared__ int psum[HSIZE];
    __shared__ int2 stage[CHUNK];  // 64 KB

    const int tid = threadIdx.x;
    const int e_all = e_adj + e_hv + e_hu;
    const int base = blockIdx.x * CHUNK;
    const int nloc = min(CHUNK, e_all - base);

    if (tid < HSIZE) hist[tid] = 0;
    __syncthreads();

    for (int i = tid; i < nloc; i += PA_BLK) {
        int t = base + i, r;
        if (t < e_adj)             r = adj_row[t];
        else if (t < e_adj + e_hv) r = HV_BASE + hv_row[t - e_adj];
        else                       r = HU_BASE + hu_row[t - e_adj - e_hv];
        int b, rl; bucket_of(r, b, rl);
        atomicAdd(&hist[b], 1);
    }
    __syncthreads();

    int v = 0;
    if (tid < HSIZE) { v = hist[tid]; psum[tid] = v; }
    __syncthreads();
    for (int off = 1; off < HSIZE; off <<= 1) {
        int t = 0;
        if (tid < HSIZE && tid >= off) t = psum[tid - off];
        __syncthreads();
        if (tid < HSIZE) psum[tid] += t;
        __syncthreads();
    }
    if (tid < HSIZE) lstart[tid] = psum[tid] - v;
    __syncthreads();

    if (tid < NBKT) {
        int c = hist[tid];
        if (c > 0)
            destB[tid] = tid * EDGE_CAP + atomicAdd(&bkt_cnt[tid], c) - lstart[tid];
    }
    __syncthreads();
    if (tid < HSIZE) hist[tid] = lstart[tid];
    __syncthreads();

    for (int i = tid; i < nloc; i += PA_BLK) {
        int t = base + i, r, c; float v2;
        if (t < e_adj)             { r = adj_row[t]; c = adj_col[t]; v2 = adj_val[t]; }
        else if (t < e_adj + e_hv) { int k = t - e_adj;
                                     r = HV_BASE + hv_row[k]; c = hv_col[k]; v2 = hv_val[k]; }
        else                       { int k = t - e_adj - e_hv;
                                     r = HU_BASE + hu_row[k]; c = hu_col[k]; v2 = hu_val[k]; }
        int b, rl; bucket_of(r, b, rl);
        int p = atomicAdd(&hist[b], 1);
        stage[p] = make_int2(c | (rl << 18), __float_as_int(v2));
    }
    __syncthreads();

    const int wave = tid >> 6, lane = tid & 63;
    for (int b = wave; b < NBKT; b += (PA_BLK / 64)) {
        int s = lstart[b];
        int e = hist[b];
        int d = destB[b];
        for (int j = s + lane; j < e; j += 64)
            tmp[d + j] = stage[j];
    }
}

__global__ void bkt_scan(const int* __restrict__ cnt, int* __restrict__ base) {
    __shared__ int s[HSIZE];
    int tid = threadIdx.x;
    int v = (tid < NBKT) ? cnt[tid] : 0;
    s[tid] = v;
    __syncthreads();
    for (int off = 1; off < HSIZE; off <<= 1) {
        int t = (tid >= off) ? s[tid - off] : 0;
        __syncthreads();
        s[tid] += t;
        __syncthreads();
    }
    if (tid < NBKT) base[tid] = s[tid] - v;
}

// ---------------------------------------------------------------------------
// Phase B: per-bucket row histogram + scan -> start[]/cnt[], counting sort ->
// CSR edges, and degree-class counting sort -> row permutation perm[]
// (rows grouped by degree so gather waves have uniform trip counts).
// ---------------------------------------------------------------------------
__global__ void __launch_bounds__(PB_BLK)
phaseB_kernel(const int* __restrict__ bkt_cnt, const int* __restrict__ bkt_base,
              const int2* __restrict__ tmp, int2* __restrict__ edges,
              int* __restrict__ start, int* __restrict__ cntArr,
              int* __restrict__ perm) {
    __shared__ int  rh[ROWS_CAP];
    __shared__ int  rs[ROWS_CAP];
    __shared__ int  psum[PB_BLK];
    __shared__ int  clsh[NCLS];
    __shared__ int  clsb[NCLS];
    __shared__ int2 stage[EDGE_CAP];  // 40 KB

    const int tid = threadIdx.x;
    const int b = blockIdx.x;
    int rlo, nR;
    if (b < NB_ADJ)              { rlo = b * ADJ_RPB;                          nR = ADJ_RPB; }
    else if (b < NB_ADJ + NB_HV) { rlo = HV_BASE + (b - NB_ADJ) * HV_RPB;      nR = HV_RPB; }
    else                         { rlo = HU_BASE + (b - NB_ADJ - NB_HV) * HU_RPB; nR = HU_RPB; }

    const int nE = bkt_cnt[b];
    const int gbase = bkt_base[b];
    const int2* src = tmp + (size_t)b * EDGE_CAP;

    rh[tid] = 0;
    rh[tid + PB_BLK] = 0;
    if (tid < NCLS) clsh[tid] = 0;
    __syncthreads();

    for (int i = tid; i < nE; i += PB_BLK) {
        int2 e = src[i];
        atomicAdd(&rh[((unsigned)e.x) >> 18], 1);
    }
    __syncthreads();

    // exclusive scan over ROWS_CAP=1024 entries, 2 per thread
    int a0 = rh[2 * tid], a1 = rh[2 * tid + 1];
    int tot = a0 + a1;
    psum[tid] = tot;
    __syncthreads();
    for (int off = 1; off < PB_BLK; off <<= 1) {
        int v = (tid >= off) ? psum[tid - off] : 0;
        __syncthreads();
        psum[tid] += v;
        __syncthreads();
    }
    int ex = psum[tid] - tot;
    rs[2 * tid]     = ex;
    rs[2 * tid + 1] = ex + a0;
    __syncthreads();

    // emit global CSR offsets
    for (int i = tid; i < nR; i += PB_BLK) {
        start[rlo + i]  = gbase + rs[i];
        cntArr[rlo + i] = rh[i];
        atomicAdd(&clsh[min(rh[i], NCLS - 1)], 1);
    }
    __syncthreads();

    // exclusive scan of the 64 class counts
    if (tid < NCLS) clsb[tid] = clsh[tid];
    __syncthreads();
    for (int off = 1; off < NCLS; off <<= 1) {
        int v = 0;
        if (tid < NCLS && tid >= off) v = clsb[tid - off];
        __syncthreads();
        if (tid < NCLS) clsb[tid] += v;
        __syncthreads();
    }
    if (tid < NCLS) clsb[tid] -= clsh[tid];
    __syncthreads();

    // emit degree-sorted permutation
    for (int i = tid; i < nR; i += PB_BLK) {
        int cls = min(rh[i], NCLS - 1);
        int pos = atomicAdd(&clsb[cls], 1);
        perm[rlo + pos] = rlo + i;
    }
    __syncthreads();

    // counting sort into stage (rs doubles as cursor), then coalesced flush
    for (int i = tid; i < nE; i += PB_BLK) {
        int2 e = src[i];
        int rl = ((unsigned)e.x) >> 18;
        int p = atomicAdd(&rs[rl], 1);
        stage[p] = make_int2(e.x & 0x3FFFF, e.y);
    }
    __syncthreads();
    for (int i = tid; i < nE; i += PB_BLK) edges[gbase + i] = stage[i];
}

// ---------------------------------------------------------------------------
// Gather core: 8 lanes per row, 2-way unrolled edge loop, fp32 accumulate.
// ---------------------------------------------------------------------------
__device__ __forceinline__ void gather_row(const int2* __restrict__ edges,
                                           const _Float16* __restrict__ x,
                                           int s, int n, int c, float* acc) {
    float acc1[8] = {0.f, 0.f, 0.f, 0.f, 0.f, 0.f, 0.f, 0.f};
    int j = s, e = s + n;
    for (; j + 1 < e; j += 2) {
        int2 e0 = edges[j], e1 = edges[j + 1];
        float v0 = __int_as_float(e0.y), v1 = __int_as_float(e1.y);
        h8 x0 = *(const h8*)(x + (size_t)e0.x * DIM + c);
        h8 x1 = *(const h8*)(x + (size_t)e1.x * DIM + c);
        #pragma unroll
        for (int k = 0; k < 8; ++k) { acc[k] += v0 * (float)x0[k]; acc1[k] += v1 * (float)x1[k]; }
    }
    if (j < e) {
        int2 e0 = edges[j];
        float v0 = __int_as_float(e0.y);
        h8 x0 = *(const h8*)(x + (size_t)e0.x * DIM + c);
        #pragma unroll
        for (int k = 0; k < 8; ++k) acc[k] += v0 * (float)x0[k];
    }
    #pragma unroll
    for (int k = 0; k < 8; ++k) acc[k] += acc1[k];
}

// K1: layer1 (T0 = A*X16 over NTOT rows) + hv biclique (bic = norm(Hv*item16))
__global__ void gatherK1(const int* __restrict__ start, const int* __restrict__ cnt,
                         const int2* __restrict__ edges, const int* __restrict__ perm,
                         const _Float16* __restrict__ X16,
                         _Float16* __restrict__ T0, _Float16* __restrict__ bic,
                         int gA) {
    int c = (threadIdx.x & 7) << 3;
    int lrow = threadIdx.x >> 3;
    if (blockIdx.x < gA) {
        int gid = blockIdx.x * 32 + lrow;
        if (gid >= NTOT) return;
        int r = perm[gid];
        float acc[8] = {0.f, 0.f, 0.f, 0.f, 0.f, 0.f, 0.f, 0.f};
        gather_row(edges, X16, start[r], cnt[r], c, acc);
        h8 o;
        #pragma unroll
        for (int k = 0; k < 8; ++k) o[k] = (_Float16)acc[k];
        *(h8*)(T0 + (size_t)r * DIM + c) = o;
    } else {
        int gid = (blockIdx.x - gA) * 32 + lrow;
        if (gid >= NBIC) return;
        int r = perm[HV_BASE + gid];
        int s = start[r], n = cnt[r];
        float acc[8] = {0.f, 0.f, 0.f, 0.f, 0.f, 0.f, 0.f, 0.f};
        gather_row(edges, X16 + (size_t)NUSERS * DIM, s, n, c, acc);
        float deg = 0.f;
        for (int j = s; j < s + n; ++j) deg += __int_as_float(edges[j].y);
        if (deg == 0.f) deg = 1.f;
        float inv = 1.f / deg;
        h8 o;
        #pragma unroll
        for (int k = 0; k < 8; ++k) o[k] = (_Float16)(acc[k] * inv);
        *(h8*)(bic + (size_t)(r - HV_BASE) * DIM + c) = o;
    }
}

// K2: layer2 (T1 = A*T0) + hu (ulocal = norm(Hu*bic))
__global__ void gatherK2(const int* __restrict__ start, const int* __restrict__ cnt,
                         const int2* __restrict__ edges, const int* __restrict__ perm,
                         const _Float16* __restrict__ T0, const _Float16* __restrict__ bic,
                         _Float16* __restrict__ T1, _Float16* __restrict__ ulocal,
                         int gA) {
    int c = (threadIdx.x & 7) << 3;
    int lrow = threadIdx.x >> 3;
    if (blockIdx.x < gA) {
        int gid = blockIdx.x * 32 + lrow;
        if (gid >= NTOT) return;
        int r = perm[gid];
        float acc[8] = {0.f, 0.f, 0.f, 0.f, 0.f, 0.f, 0.f, 0.f};
        gather_row(edges, T0, start[r], cnt[r], c, acc);
        h8 o;
        #pragma unroll
        for (int k = 0; k < 8; ++k) o[k] = (_Float16)acc[k];
        *(h8*)(T1 + (size_t)r * DIM + c) = o;
    } else {
        int gid = (blockIdx.x - gA) * 32 + lrow;
        if (gid >= NUSERS) return;
        int r = perm[HU_BASE + gid];
        int s = start[r], n = cnt[r];
        float acc[8] = {0.f, 0.f, 0.f, 0.f, 0.f, 0.f, 0.f, 0.f};
        gather_row(edges, bic, s, n, c, acc);
        float deg = 0.f;
        for (int j = s; j < s + n; ++j) deg += __int_as_float(edges[j].y);
        if (deg == 0.f) deg = 1.f;
        float inv = 1.f / deg;
        h8 o;
        #pragma unroll
        for (int k = 0; k < 8; ++k) o[k] = (_Float16)(acc[k] * inv);
        *(h8*)(ulocal + (size_t)(r - HU_BASE) * DIM + c) = o;
    }
}

// K3: layer3 + epilogue: out = 0.25*(x0+t0+t1+gather(T1)) [+ ulocal users]
__global__ void gatherK3(const int* __restrict__ start, const int* __restrict__ cnt,
                         const int2* __restrict__ edges, const int* __restrict__ perm,
                         const _Float16* __restrict__ X16,
                         const _Float16* __restrict__ T0,
                         const _Float16* __restrict__ T1,
                         const _Float16* __restrict__ ulocal,
                         float* __restrict__ out) {
    int gid = blockIdx.x * 32 + (threadIdx.x >> 3);
    if (gid >= NTOT) return;
    int c = (threadIdx.x & 7) << 3;
    int r = perm[gid];
    float acc[8] = {0.f, 0.f, 0.f, 0.f, 0.f, 0.f, 0.f, 0.f};
    gather_row(edges, T1, start[r], cnt[r], c, acc);
    size_t o = (size_t)r * DIM + c;
    h8 x0 = *(const h8*)(X16 + o);
    h8 t0 = *(const h8*)(T0 + o);
    h8 t1 = *(const h8*)(T1 + o);
    float rr[8];
    #pragma unroll
    for (int k = 0; k < 8; ++k)
        rr[k] = 0.25f * ((float)x0[k] + (float)t0[k] + (float)t1[k] + acc[k]);
    if (r < NUSERS) {
        h8 ul = *(const h8*)(ulocal + o);
        #pragma unroll
        for (int k = 0; k < 8; ++k) rr[k] += (float)ul[k];
    }
    float4 lo = make_float4(rr[0], rr[1], rr[2], rr[3]);
    float4 hi = make_float4(rr[4], rr[5], rr[6], rr[7]);
    float4* op = (float4*)(out + o);
    op[0] = lo;
    op[1] = hi;
}

// ---------------------------------------------------------------------------
extern "C" void kernel_launch(void* const* d_in, const int* in_sizes, int n_in,
                              void* d_out, int out_size, void* d_ws, size_t ws_size,
                              hipStream_t stream) {
    const float* user_emb = (const float*)d_in[0];
    const float* item_emb = (const float*)d_in[1];
    const float* adj_val  = (const float*)d_in[2];
    const float* hv_val   = (const float*)d_in[3];
    const float* hu_val   = (const float*)d_in[4];
    const int*   adj_row  = (const int*)d_in[5];
    const int*   adj_col  = (const int*)d_in[6];
    const int*   hv_row   = (const int*)d_in[7];
    const int*   hv_col   = (const int*)d_in[8];
    const int*   hu_row   = (const int*)d_in[9];
    const int*   hu_col   = (const int*)d_in[10];

    const int E_ADJ = in_sizes[2];
    const int E_HV  = in_sizes[3];
    const int E_HU  = in_sizes[4];
    const int E_ALL = E_ADJ + E_HV + E_HU;

    // -------- workspace carve-up (256B-aligned) --------
    char* ws = (char*)d_ws;
    auto alloc = [&](size_t bytes) -> char* {
        char* p = ws;
        ws += (bytes + 255) & ~(size_t)255;
        return p;
    };
    const size_t SZ_H = (size_t)NTOT * DIM * sizeof(_Float16);   // 19.2 MB
    _Float16* X16     = (_Float16*)alloc(SZ_H);
    _Float16* T0      = (_Float16*)alloc(SZ_H);
    _Float16* T1      = (_Float16*)alloc(SZ_H);
    _Float16* bic     = (_Float16*)alloc((size_t)NBIC * DIM * sizeof(_Float16));
    _Float16* ulocal  = (_Float16*)alloc((size_t)NUSERS * DIM * sizeof(_Float16));
    int*   cnt      = (int*)alloc((size_t)NROWS_ALL * sizeof(int));
    int*   start    = (int*)alloc((size_t)NROWS_ALL * sizeof(int));
    int*   perm     = (int*)alloc((size_t)NROWS_ALL * sizeof(int));
    int2*  edges    = (int2*)alloc((size_t)E_ALL * sizeof(int2));
    int2*  tmp      = (int2*)alloc((size_t)NBKT * EDGE_CAP * sizeof(int2));  // 20.5 MB
    int*   bkt_cnt  = (int*)alloc(NBKT * sizeof(int));
    int*   bkt_base = (int*)alloc(NBKT * sizeof(int));

    const int BLK = 256;
    auto cdiv = [](int a, int b) { return (a + b - 1) / b; };

    // ---- CSR build ----
    hipMemsetAsync(bkt_cnt, 0, NBKT * sizeof(int), stream);
    phaseA_kernel<<<cdiv(E_ALL, CHUNK), PA_BLK, 0, stream>>>(adj_row, adj_col, adj_val,
                                                             hv_row, hv_col, hv_val,
                                                             hu_row, hu_col, hu_val,
                                                             bkt_cnt, tmp, E_ADJ, E_HV, E_HU);
    to_half_kernel<<<cdiv(NTOT * DIM / 8, BLK), BLK, 0, stream>>>(user_emb, item_emb, X16);
    bkt_scan<<<1, HSIZE, 0, stream>>>(bkt_cnt, bkt_base);
    phaseB_kernel<<<NBKT, PB_BLK, 0, stream>>>(bkt_cnt, bkt_base, tmp, edges,
                                               start, cnt, perm);

    // ---- fused gathers (32 rows per 256-thread block) ----
    const int gA  = cdiv(NTOT, 32);
    const int gHV = cdiv(NBIC, 32);
    const int gHU = cdiv(NUSERS, 32);

    gatherK1<<<gA + gHV, BLK, 0, stream>>>(start, cnt, edges, perm, X16, T0, bic, gA);
    gatherK2<<<gA + gHU, BLK, 0, stream>>>(start, cnt, edges, perm, T0, bic, T1, ulocal, gA);
    gatherK3<<<gA, BLK, 0, stream>>>(start, cnt, edges, perm, X16, T0, T1, ulocal,
                                     (float*)d_out);
}